// Round 13
// baseline (1815.600 us; speedup 1.0000x reference)
//
#include <hip/hip_runtime.h>
#include <cstdint>

typedef _Float16 f16;
typedef __attribute__((ext_vector_type(2))) _Float16 f16x2;
typedef __attribute__((ext_vector_type(8))) _Float16 f16x8;
typedef __attribute__((ext_vector_type(4))) float f32x4;
typedef __attribute__((ext_vector_type(2))) float f32x2;
typedef __attribute__((ext_vector_type(8))) unsigned short us8;   // 16 B — staging vector
typedef __attribute__((ext_vector_type(4))) int i32x4;

#define NB   32
#define TIN  1600
#define CIN  80
#define TOUT 800
#define DH   512
#define NV   1000
#define NU   200
#define TXP  1604   // xpad time rows (1 left pad + 1600 + 3 tail)
#define THP  804    // conv buffer time rows (2 pad each side)
#define EPSB 1e-3f
#define EWG  248    // encoder worker blocks in the fused kernel (8+248 = 256 = #CUs)
#define NITEM (13 * 32)   // decode items: 13 u-tiles x 32 batches

// write-through (coherence-point) stores — R4/R5-proven
__device__ __forceinline__ void st_sys_f16(f16* p, float v)
{
    f16 h = (f16)v;
    short s; __builtin_memcpy(&s, &h, 2);
    int si = (int)s;
    asm volatile("global_store_short %0, %1, off sc0 sc1"
                 :: "v"(p), "v"(si) : "memory");
}
__device__ __forceinline__ void st_sys_i32(int* p, int v)
{
    asm volatile("global_store_dword %0, %1, off sc0 sc1"
                 :: "v"(p), "v"(v) : "memory");
}

// Sentinel-gated fragment batch load (R4/R8-proven): 16 x dwordx4 (sc1, bypasses stale
// L2) from base + ks*64B. Retries until no f16 half equals the 0x7FFF NaN poison.
// 64 VGPRs live per call — stays under the 256 arch-VGPR cap.
template<int SLEEP>
__device__ __forceinline__ void poll_h16(const f16* base, f16x8 v[16])
{
    while (true) {
        asm volatile(
            "global_load_dwordx4 %0, %16, off sc1\n\t"
            "global_load_dwordx4 %1, %16, off offset:64 sc1\n\t"
            "global_load_dwordx4 %2, %16, off offset:128 sc1\n\t"
            "global_load_dwordx4 %3, %16, off offset:192 sc1\n\t"
            "global_load_dwordx4 %4, %16, off offset:256 sc1\n\t"
            "global_load_dwordx4 %5, %16, off offset:320 sc1\n\t"
            "global_load_dwordx4 %6, %16, off offset:384 sc1\n\t"
            "global_load_dwordx4 %7, %16, off offset:448 sc1\n\t"
            "global_load_dwordx4 %8, %16, off offset:512 sc1\n\t"
            "global_load_dwordx4 %9, %16, off offset:576 sc1\n\t"
            "global_load_dwordx4 %10, %16, off offset:640 sc1\n\t"
            "global_load_dwordx4 %11, %16, off offset:704 sc1\n\t"
            "global_load_dwordx4 %12, %16, off offset:768 sc1\n\t"
            "global_load_dwordx4 %13, %16, off offset:832 sc1\n\t"
            "global_load_dwordx4 %14, %16, off offset:896 sc1\n\t"
            "global_load_dwordx4 %15, %16, off offset:960 sc1\n\t"
            "s_waitcnt vmcnt(0)"
            : "=&v"(v[0]), "=&v"(v[1]), "=&v"(v[2]), "=&v"(v[3]),
              "=&v"(v[4]), "=&v"(v[5]), "=&v"(v[6]), "=&v"(v[7]),
              "=&v"(v[8]), "=&v"(v[9]), "=&v"(v[10]), "=&v"(v[11]),
              "=&v"(v[12]), "=&v"(v[13]), "=&v"(v[14]), "=&v"(v[15])
            : "v"(base)
            : "memory");
        f16x8 s0 = v[0] + v[1],   s1 = v[2] + v[3];
        f16x8 s2 = v[4] + v[5],   s3 = v[6] + v[7];
        f16x8 s4 = v[8] + v[9],   s5 = v[10] + v[11];
        f16x8 s6 = v[12] + v[13], s7 = v[14] + v[15];
        s0 += s1; s2 += s3; s4 += s5; s6 += s7;
        s0 += s2; s4 += s6; s0 += s4;
        float r = (float)s0[0] + (float)s0[1] + (float)s0[2] + (float)s0[3]
                + (float)s0[4] + (float)s0[5] + (float)s0[6] + (float)s0[7];
        if (!__any(r != r)) return;
        __builtin_amdgcn_s_sleep(SLEEP);
    }
}

// Cheap progress wait (R5-proven poll shape): 8 flag words in ONE 32-byte check.
// 500x less poll traffic than re-fetching the 16 KB h-tile per retry (R12's mistake).
__device__ __forceinline__ void wait_flags(const int* fl, int target)
{
    i32x4 a, b;
    while (true) {
        asm volatile("global_load_dwordx4 %0, %2, off sc1\n\t"
                     "global_load_dwordx4 %1, %3, off sc1\n\t"
                     "s_waitcnt vmcnt(0)"
                     : "=&v"(a), "=&v"(b)
                     : "v"(fl), "v"(fl + 4)
                     : "memory");
        if (a.x >= target && a.y >= target && a.z >= target && a.w >= target &&
            b.x >= target && b.y >= target && b.z >= target && b.w >= target) break;
        __builtin_amdgcn_s_sleep(64);
    }
}

__device__ __forceinline__ float fast_tanh(float x)
{
    return 1.f - 2.f / (__expf(2.f * x) + 1.f);
}

// ---------------------------------------------------------------- init
__global__ void init_zero(float* gsum, float* gsumsq,
                          int* lcnt, int* gflag, f16* xpad, f16* hbufA, f16* hbufB,
                          f16* Hc)
{
    int tid = blockIdx.x * 256 + threadIdx.x;
    int stride = gridDim.x * 256;
    if (blockIdx.x == 0) {
        if (threadIdx.x < 80) { gsum[threadIdx.x] = 0.f; gsumsq[threadIdx.x] = 0.f; }
        if (threadIdx.x >= 128 && threadIdx.x < 144) lcnt[threadIdx.x - 128] = 0;
        if (threadIdx.x >= 160 && threadIdx.x < 168) gflag[threadIdx.x - 160] = 0;
    }
    // xpad zero rows: t'=0, 1601..1603 per b
    for (int i = tid; i < NB * 4 * CIN; i += stride) {
        int b = i / (4 * CIN), rr = (i / CIN) % 4, c = i % CIN;
        int row = (rr == 0) ? 0 : (1600 + rr);
        xpad[((long)b * TXP + row) * CIN + c] = (f16)0.f;
    }
    // hbuf zero rows: t'=0,1,802,803 per b, both buffers
    for (int i = tid; i < 2 * NB * 4 * DH; i += stride) {
        int q = i; int buf = q / (NB * 4 * DH); q %= NB * 4 * DH;
        int b = q / (4 * DH); int rr = (q / DH) % 4; int dd = q % DH;
        int row = (rr < 2) ? rr : (800 + rr);
        f16* hb = buf ? hbufB : hbufA;
        hb[((long)b * THP + row) * DH + dd] = (f16)0.f;
    }
    // Hc h-region NaN poison (cols 0..511 of all 6400 rows) for the sentinel protocol
    us8 sent;
#pragma unroll
    for (int e = 0; e < 8; e++) sent[e] = 0x7FFFu;
    for (int i = tid; i < 6400 * 64; i += stride)
        *(us8*)&Hc[(long)(i >> 6) * 1024 + (i & 63) * 8] = sent;
}

// ---------------------------------------------------------------- transpose f32 -> f16 (out[c][r] = in[r][c], OOB -> 0)
__global__ void transpose_f32_f16(const float* __restrict__ in, int R, int C,
                                  f16* __restrict__ out, int outRows, int outCols)
{
    __shared__ float t[32][33];
    int c0 = blockIdx.x * 32, r0 = blockIdx.y * 32;
    int x = threadIdx.x & 31, y = threadIdx.x >> 5;
    for (int i = y; i < 32; i += 8) {
        int r = r0 + i, c = c0 + x;
        t[i][x] = (r < R && c < C) ? in[(long)r * C + c] : 0.0f;
    }
    __syncthreads();
    for (int i = y; i < 32; i += 8) {
        int orow = c0 + i, ocol = r0 + x;
        if (orow < outRows && ocol < outCols)
            out[(long)orow * outCols + ocol] = (f16)t[x][i];
    }
}

// ---------------------------------------------------------------- batchnorm
__global__ void bn_stats(const float* __restrict__ x, float* gsum, float* gsumsq)
{
    __shared__ float ls[240], ls2[240];
    const float* base = x + (long)blockIdx.x * 200 * CIN;
    int tid = threadIdx.x;
    if (tid < 240) {
        int c = tid % 80, rg = tid / 80;
        float s = 0.f, s2 = 0.f;
        for (int r = rg; r < 200; r += 3) {
            float v = base[r * CIN + c];
            s += v; s2 += v * v;
        }
        ls[tid] = s; ls2[tid] = s2;
    }
    __syncthreads();
    if (tid < 80) {
        atomicAdd(&gsum[tid],   ls[tid] + ls[tid + 80] + ls[tid + 160]);
        atomicAdd(&gsumsq[tid], ls2[tid] + ls2[tid + 80] + ls2[tid + 160]);
    }
}

__global__ void bn_apply(const float* __restrict__ x, const float* __restrict__ gsum,
                         const float* __restrict__ gsumsq, const float* __restrict__ gamma,
                         const float* __restrict__ beta, f16* __restrict__ xpad)
{
    long idx = (long)blockIdx.x * 256 + threadIdx.x;
    if (idx >= (long)NB * TIN * CIN) return;
    int c = (int)(idx % CIN);
    long bt = idx / CIN;
    int t = (int)(bt % TIN); int b = (int)(bt / TIN);
    float mean = gsum[c] * (1.f / 51200.f);
    float var  = gsumsq[c] * (1.f / 51200.f) - mean * mean;
    float sc = gamma[c] * rsqrtf(var + EPSB);
    float sh = beta[c] - mean * sc;
    xpad[((long)b * TXP + t + 1) * CIN + c] = (f16)(x[idx] * sc + sh);
}

// ---------------------------------------------------------------- encoder layer worker (inside fused kernel)
// One layer = 1664 tiles (32 batches x 13 Mtiles x 4 Ntiles), M=800, N=512.
__device__ void enc_layer(int eb, int tid,
                          const f16* __restrict__ Ab, long strideA, long slabA,
                          const f16* __restrict__ Bb, long strideB,
                          int Kchunks, const float* __restrict__ bias,
                          const f16* __restrict__ resid, f16* __restrict__ outH,
                          long slabRO, f16 As[][72], f16 Bs[][72])
{
    const int lane = tid & 63, wv = tid >> 6;
    const int lm = lane & 15, lk = lane >> 4;
    const int srow = tid >> 3, scol = (tid & 7) * 8;
    f32x4 vzero = {0.f, 0.f, 0.f, 0.f};

    for (int t = eb; t < 1664; t += EWG) {
        int b = t / 52, rem = t - b * 52;
        int m0 = (rem >> 2) * 64, n0 = (rem & 3) * 128;
        const f16* Abase = Ab + (long)b * slabA;

        f32x4 acc[4][2];
#pragma unroll
        for (int i = 0; i < 4; i++) { acc[i][0] = vzero; acc[i][1] = vzero; }

        for (int kc = 0; kc < Kchunks; kc++) {
            int kb = kc * 64;
#pragma unroll
            for (int p = 0; p < 2; p++) {
                int r = srow + p * 32;
                int m = m0 + r; if (m > 799) m = 799;
                *(us8*)&As[r][scol] = *(const us8*)(Abase + (long)m * strideA + kb + scol);
            }
#pragma unroll
            for (int p = 0; p < 4; p++) {
                int r = srow + p * 32;
                *(us8*)&Bs[r][scol] = *(const us8*)(Bb + (long)(n0 + r) * strideB + kb + scol);
            }
            __syncthreads();
#pragma unroll
            for (int ks = 0; ks < 2; ks++) {
                f16x8 af[4], bf[2];
#pragma unroll
                for (int mt = 0; mt < 4; mt++)
                    af[mt] = *(const f16x8*)&As[mt * 16 + lm][ks * 32 + lk * 8];
#pragma unroll
                for (int nt = 0; nt < 2; nt++)
                    bf[nt] = *(const f16x8*)&Bs[wv * 32 + nt * 16 + lm][ks * 32 + lk * 8];
#pragma unroll
                for (int mt = 0; mt < 4; mt++)
#pragma unroll
                    for (int nt = 0; nt < 2; nt++)
                        acc[mt][nt] = __builtin_amdgcn_mfma_f32_16x16x32_f16(af[mt], bf[nt], acc[mt][nt], 0, 0, 0);
            }
            __syncthreads();
        }
#pragma unroll
        for (int mt = 0; mt < 4; mt++) {
#pragma unroll
            for (int nt = 0; nt < 2; nt++) {
                int n = n0 + wv * 32 + nt * 16 + lm;
#pragma unroll
                for (int reg = 0; reg < 4; reg++) {
                    int m = m0 + mt * 16 + lk * 4 + reg;
                    if (m >= 800) continue;
                    float v = acc[mt][nt][reg] + bias[n];
                    v = v > 0.f ? v : 0.f;
                    if (resid) v += (float)resid[(long)b * slabRO + (long)(2 + m) * DH + n];
                    outH[(long)b * slabRO + (long)(2 + m) * DH + n] = (f16)v;
                }
            }
        }
    }
}

// ---------------------------------------------------------------- fused mega-kernel:
// blocks 0..7   = GRU (R8 sentinel exchange on the hot path) + coarse progress flags
//                 (every 16 steps: drain -> barrier -> gflag[g]=u+1; ~4us total)
// blocks 8..255 = encoder conv chain, then FLAG-GATED streaming decode: wait on the
//                 32-byte flag line (not 16KB data polls — R12's poll storm slowed the
//                 GRU 330us), then one sentinel load + scores/softmax/ctx/fc.
__launch_bounds__(256, 1)
__global__ void enc_gru(const f16* __restrict__ wrecT, const float* __restrict__ gk,
                        const float* __restrict__ gbias, const int* __restrict__ ytrue,
                        f16* __restrict__ Hc,
                        const f16* __restrict__ xpad, const f16* __restrict__ w0T,
                        const float* __restrict__ b0, const f16* __restrict__ tcrT,
                        const float* __restrict__ tcrb,
                        f16* __restrict__ hbufA, f16* __restrict__ hbufB,
                        int* __restrict__ lcnt, int* __restrict__ gflag,
                        const f16* __restrict__ fcT, const float* __restrict__ fcb,
                        float* __restrict__ out)
{
    // one LDS arena, manually overlaid per phase:
    //  GRU:    yl int[6400]                                (25.6 KB)
    //  conv:   As f16[64][72] @0, Bs f16[128][72] @9216    (27.6 KB)
    //  decode: al f32[800][18] @0 (ctxT f16[16][520] overlays @0 after al dies),
    //          red @57600, red2 @57616, itemP @57632       (57.7 KB)
    __shared__ __align__(16) char smem[57664];
    const int tid = threadIdx.x;

    if (blockIdx.x < 8) {
        // ==================== GRU (R8 verbatim + coarse flags) ====================
        int* yl = (int*)smem;
        const int lane = tid & 63, wv = tid >> 6;
        const int gw = (int)blockIdx.x * 4 + wv;
        const int lm = lane & 15, lk = lane >> 4;
        const int j = gw * 16 + lm;

        for (int i = tid; i < NU * 32; i += 256) {
            int b = i / NU, u = i - b * NU;
            yl[u * 32 + b] = ytrue[b * 201 + u];
        }

        f16x8 wf[3][16];
#pragma unroll
        for (int g = 0; g < 3; g++)
#pragma unroll
            for (int ks = 0; ks < 16; ks++) {
                wf[g][ks] = *(const f16x8*)&wrecT[(long)(g * 512 + j) * 512 + ks * 32 + lk * 8];
                asm volatile("" : "+v"(wf[g][ks]));
            }

        const float biz = gbias[j],        bir = gbias[512 + j],        bic = gbias[1024 + j];
        const float brz = gbias[1536 + j], brr = gbias[1536 + 512 + j], brc = gbias[1536 + 1024 + j];
        f32x4 vzero = {0.f, 0.f, 0.f, 0.f};

        __syncthreads();

        float hold[8];
        float nxz[8], nxr[8], nxh[8], mxz[8], mxr[8], mxh[8];
#pragma unroll
        for (int s = 0; s < 8; s++) {
            hold[s] = 0.f;
            int b = ((s >> 2) << 4) + lk * 4 + (s & 3);
            const float* gkr = gk + (long)yl[b] * 1536;
            nxz[s] = gkr[j]; nxr[s] = gkr[512 + j]; nxh[s] = gkr[1024 + j];
        }

        for (int u = 0; u < NU; u++) {
            int up = (u < NU - 1) ? u + 1 : u;
#pragma unroll
            for (int s = 0; s < 8; s++) {
                int b = ((s >> 2) << 4) + lk * 4 + (s & 3);
                const float* gkr = gk + (long)yl[up * 32 + b] * 1536;
                mxz[s] = gkr[j]; mxr[s] = gkr[512 + j]; mxh[s] = gkr[1024 + j];
            }

            f32x4 acc[3][2];
#pragma unroll
            for (int g = 0; g < 3; g++) { acc[g][0] = vzero; acc[g][1] = vzero; }

            if (u > 0) {
                const f16* baseA = Hc + ((long)(u - 1) * 32 + lm) * 1024 + lk * 8;
                {
                    f16x8 va[16];
                    poll_h16<1>(baseA, va);
#pragma unroll
                    for (int ks = 0; ks < 16; ks++)
#pragma unroll
                        for (int g = 0; g < 3; g++)
                            acc[g][0] = __builtin_amdgcn_mfma_f32_16x16x32_f16(va[ks], wf[g][ks], acc[g][0], 0, 0, 0);
                }
                {
                    f16x8 vb[16];
                    poll_h16<1>(baseA + 16 * 1024, vb);
#pragma unroll
                    for (int ks = 0; ks < 16; ks++)
#pragma unroll
                        for (int g = 0; g < 3; g++)
                            acc[g][1] = __builtin_amdgcn_mfma_f32_16x16x32_f16(vb[ks], wf[g][ks], acc[g][1], 0, 0, 0);
                }
            }

#pragma unroll
            for (int mt = 0; mt < 2; mt++) {
#pragma unroll
                for (int reg = 0; reg < 4; reg++) {
                    int s = mt * 4 + reg;
                    int b = mt * 16 + lk * 4 + reg;
                    float hz = acc[0][mt][reg] + brz;
                    float hr = acc[1][mt][reg] + brr;
                    float hh = acc[2][mt][reg] + brc;
                    float z = 1.f / (1.f + __expf(-(nxz[s] + biz + hz)));
                    float r = 1.f / (1.f + __expf(-(nxr[s] + bir + hr)));
                    float cd = fast_tanh(nxh[s] + bic + r * hh);
                    float hnew = z * hold[s] + (1.f - z) * cd;
                    hold[s] = hnew;
                    st_sys_f16(&Hc[((long)u * 32 + b) * 1024 + j], hnew);
                }
            }
#pragma unroll
            for (int s = 0; s < 8; s++) { nxz[s] = mxz[s]; nxr[s] = mxr[s]; nxh[s] = mxh[s]; }

            // coarse progress flag for decode consumers (R5-proven drain->barrier->store;
            // 13x per run, off the per-step critical path)
            if ((u & 15) == 15 || u == NU - 1) {
                asm volatile("s_waitcnt vmcnt(0)" ::: "memory");
                __syncthreads();
                if (tid == 0) st_sys_i32(&gflag[(int)blockIdx.x], u + 1);
            }
        }
        asm volatile("s_waitcnt vmcnt(0)" ::: "memory");
        return;
    }

    // ==================== encoder workers ====================
    f16 (*As)[72] = (f16(*)[72])smem;
    f16 (*Bs)[72] = (f16(*)[72])(smem + 64 * 72 * 2);
    const int eb = (int)blockIdx.x - 8;
    const int lane = tid & 63, wv = tid >> 6;
    const int lm = lane & 15, lk = lane >> 4;
    f32x4 vzero = {0.f, 0.f, 0.f, 0.f};

    // layer 0: conv0
    enc_layer(eb, tid, xpad, 160, (long)TXP * CIN, w0T, 448, 7, b0,
              nullptr, hbufA, (long)THP * DH, As, Bs);

    const f16* tin = hbufA; f16* tout = hbufB;
    for (int L = 0; L < 4; L++) {
        // barrier: publish layer L-output (release), wait all, invalidate (acquire)
        __syncthreads();
        if (tid == 0) {
            __hip_atomic_fetch_add(&lcnt[L], 1, __ATOMIC_RELEASE, __HIP_MEMORY_SCOPE_AGENT);
            while (__hip_atomic_load(&lcnt[L], __ATOMIC_RELAXED, __HIP_MEMORY_SCOPE_AGENT) < EWG)
                __builtin_amdgcn_s_sleep(8);
            (void)__hip_atomic_load(&lcnt[L], __ATOMIC_ACQUIRE, __HIP_MEMORY_SCOPE_AGENT);
        }
        __syncthreads();

        enc_layer(eb, tid, tin, 512, (long)THP * DH, tcrT + (size_t)L * 512 * 2560, 2560,
                  40, tcrb + L * 512, tin, tout, (long)THP * DH, As, Bs);
        const f16* t2 = tout; tout = (f16*)tin; tin = t2;
    }

    // publish layer-4 output (enc = hbufA) to all worker blocks (same proven pattern)
    __syncthreads();
    if (tid == 0) {
        __hip_atomic_fetch_add(&lcnt[4], 1, __ATOMIC_RELEASE, __HIP_MEMORY_SCOPE_AGENT);
        while (__hip_atomic_load(&lcnt[4], __ATOMIC_RELAXED, __HIP_MEMORY_SCOPE_AGENT) < EWG)
            __builtin_amdgcn_s_sleep(8);
        (void)__hip_atomic_load(&lcnt[4], __ATOMIC_ACQUIRE, __HIP_MEMORY_SCOPE_AGENT);
    }
    __syncthreads();

    // ==================== flag-gated streaming decode ====================
    const f16* enc = hbufA;   // final encoder output (after 4 ping-pong swaps)
    float (*al)[18] = (float(*)[18])smem;
    float* red  = (float*)(smem + 57600);
    float* red2 = (float*)(smem + 57616);
    int*   itemP = (int*)(smem + 57632);
    f16*   ctxT = (f16*)smem;              // [16][520] overlay, live only after al dies

    while (true) {
        __syncthreads();                    // protect itemP + smem reuse across items
        if (tid == 0)
            *itemP = __hip_atomic_fetch_add(&lcnt[8], 1, __ATOMIC_RELAXED, __HIP_MEMORY_SCOPE_AGENT);
        __syncthreads();
        const int item = *itemP;
        if (item >= NITEM) break;
        const int ut = item >> 5, b = item & 31;
        const int u0 = ut * 16;

        // ---- gate: wait until ALL 8 GRU blocks published rows through this u-tile ----
        {
            int tgt = u0 + 15; if (tgt > NU - 1) tgt = NU - 1;
            wait_flags(gflag, tgt + 1);     // 32-byte poll, sleep 64 — near-zero L3 load
        }

        // ---- phase 1: sentinel A-fragments (succeeds first try post-flag) + scores ----
        int ua = u0 + lm; if (ua > NU - 1) ua = NU - 1;
        f16x8 af[16];
        poll_h16<8>(Hc + ((long)ua * 32 + b) * 1024 + lk * 8, af);

        const f16* encb = enc + ((long)b * THP + 2) * DH;
        for (int nt = wv; nt < 50; nt += 4) {          // 50 t-tiles of 16, 4 waves
            const f16* brow = encb + (long)(nt * 16 + lm) * DH + lk * 8;
            f32x4 acc = vzero;
#pragma unroll
            for (int kc = 0; kc < 16; kc++) {           // same K order as old gemm16<2>
                f16x8 bf = *(const f16x8*)(brow + kc * 32);
                acc = __builtin_amdgcn_mfma_f32_16x16x32_f16(af[kc], bf, acc, 0, 0, 0);
            }
            const int t = nt * 16 + lm;
#pragma unroll
            for (int reg = 0; reg < 4; reg++)
                al[t][lk * 4 + reg] = acc[reg];
        }
        __syncthreads();

        // ---- phase 2: softmax each valid row (R11/R12-proven, identical op order) ----
        for (int ul = 0; ul < 16; ul++) {
            int u = u0 + ul;
            if (u < NU) {
                float v[4]; float mx = -1e30f;
#pragma unroll
                for (int i = 0; i < 4; i++) {
                    int idx = tid + i * 256;
                    v[i] = (idx < 800) ? al[idx][ul] : -1e30f;
                    mx = fmaxf(mx, v[i]);
                }
#pragma unroll
                for (int off = 32; off; off >>= 1) mx = fmaxf(mx, __shfl_xor(mx, off));
                if ((tid & 63) == 0) red[tid >> 6] = mx;
                __syncthreads();
                mx = fmaxf(fmaxf(red[0], red[1]), fmaxf(red[2], red[3]));
                float sum = 0.f;
#pragma unroll
                for (int i = 0; i < 4; i++) { v[i] = __expf(v[i] - mx); sum += v[i]; }
#pragma unroll
                for (int off = 32; off; off >>= 1) sum += __shfl_xor(sum, off);
                if ((tid & 63) == 0) red2[tid >> 6] = sum;
                __syncthreads();
                float s = red2[0] + red2[1] + red2[2] + red2[3];
                float inv = 1.f / s;
#pragma unroll
                for (int i = 0; i < 4; i++) {
                    int idx = tid + i * 256;
                    if (idx < 800) al[idx][ul] = v[i] * inv;
                }
                __syncthreads();
            } else {
                for (int t = tid; t < 800; t += 256) al[t][ul] = 0.f;
            }
        }
        __syncthreads();

        // ---- phase 3: ctx = alpha @ enc (proven VALU loop, verbatim) ----
        int d0 = tid * 2;
        float a0[16], a1[16];
#pragma unroll
        for (int i = 0; i < 16; i++) { a0[i] = 0.f; a1[i] = 0.f; }
        const f16* encd = enc + ((long)b * THP + 2) * DH + d0;
        for (int t = 0; t < 800; t++) {
            f16x2 e = *(const f16x2*)&encd[(long)t * DH];
            float f0 = (float)e.x, f1 = (float)e.y;
#pragma unroll
            for (int g = 0; g < 8; g++) {
                f32x2 ap = *(const f32x2*)&al[t][2 * g];
                a0[2 * g]     += ap.x * f0; a0[2 * g + 1] += ap.y * f0;
                a1[2 * g]     += ap.x * f1; a1[2 * g + 1] += ap.y * f1;
            }
        }
        __syncthreads();   // al fully consumed; safe to overlay ctxT

        // ctx tile -> f16 in LDS (same cast as the old ctx_kernel Hc write)
#pragma unroll
        for (int ul = 0; ul < 16; ul++) {
            ctxT[ul * 520 + d0]     = (f16)a0[ul];
            ctxT[ul * 520 + d0 + 1] = (f16)a1[ul];
        }
        __syncthreads();

        // ---- phase 4: fc logits (same ascending k-chunk order as old gemm16<3>) ----
        f16x8 cf[16];
#pragma unroll
        for (int kc = 0; kc < 16; kc++)
            cf[kc] = *(const f16x8*)&ctxT[lm * 520 + kc * 32 + lk * 8];

        for (int nt = wv; nt < 63; nt += 4) {          // 63 n-tiles of 16 cover 1000
            const int n0 = nt * 16;
            const f16* brow = fcT + (long)(n0 + lm) * 1024 + lk * 8;
            f32x4 acc = vzero;
#pragma unroll
            for (int kc = 0; kc < 16; kc++) {           // k = 0..511 (h half)
                f16x8 bf = *(const f16x8*)(brow + kc * 32);
                acc = __builtin_amdgcn_mfma_f32_16x16x32_f16(af[kc], bf, acc, 0, 0, 0);
            }
#pragma unroll
            for (int kc = 0; kc < 16; kc++) {           // k = 512..1023 (ctx half)
                f16x8 bf = *(const f16x8*)(brow + 512 + kc * 32);
                acc = __builtin_amdgcn_mfma_f32_16x16x32_f16(cf[kc], bf, acc, 0, 0, 0);
            }
#pragma unroll
            for (int reg = 0; reg < 4; reg++) {
                int u = u0 + lk * 4 + reg, n = n0 + lm;
                if (u < NU && n < 1000)
                    out[((long)b * NU + u) * 1000 + n] = acc[reg] + fcb[n];
            }
        }
    }
}

// ---------------------------------------------------------------- row softmax in place (len <= 1024) — final output only
__global__ void row_softmax(float* __restrict__ base, int len)
{
    float* s = base + (long)blockIdx.x * len;
    int tid = threadIdx.x;
    float v[4]; float mx = -1e30f;
#pragma unroll
    for (int i = 0; i < 4; i++) {
        int idx = tid + i * 256;
        v[i] = (idx < len) ? s[idx] : -1e30f;
        mx = fmaxf(mx, v[i]);
    }
#pragma unroll
    for (int off = 32; off; off >>= 1) mx = fmaxf(mx, __shfl_xor(mx, off));
    __shared__ float red[4], red2[4];
    if ((tid & 63) == 0) red[tid >> 6] = mx;
    __syncthreads();
    mx = fmaxf(fmaxf(red[0], red[1]), fmaxf(red[2], red[3]));
    float sum = 0.f;
#pragma unroll
    for (int i = 0; i < 4; i++) { v[i] = __expf(v[i] - mx); sum += v[i]; }
#pragma unroll
    for (int off = 32; off; off >>= 1) sum += __shfl_xor(sum, off);
    if ((tid & 63) == 0) red2[tid >> 6] = sum;
    __syncthreads();
    sum = red2[0] + red2[1] + red2[2] + red2[3];
    float inv = 1.f / sum;
#pragma unroll
    for (int i = 0; i < 4; i++) {
        int idx = tid + i * 256;
        if (idx < len) s[idx] = v[i] * inv;
    }
}

// ---------------------------------------------------------------- launcher
extern "C" void kernel_launch(void* const* d_in, const int* in_sizes, int n_in,
                              void* d_out, int out_size, void* d_ws, size_t ws_size,
                              hipStream_t stream)
{
    const float* x     = (const float*)d_in[0];
    const int*   ytrue = (const int*)d_in[1];
    const float* gamma = (const float*)d_in[2];
    const float* beta  = (const float*)d_in[3];
    const float* w0    = (const float*)d_in[4];
    const float* b0    = (const float*)d_in[5];
    const float* tcrw  = (const float*)d_in[6];
    const float* tcrb  = (const float*)d_in[7];
    const float* gk    = (const float*)d_in[8];
    const float* grk   = (const float*)d_in[9];
    const float* gbias = (const float*)d_in[10];
    const float* fcw   = (const float*)d_in[11];
    const float* fcb   = (const float*)d_in[12];
    float* out = (float*)d_out;
    (void)in_sizes; (void)n_in; (void)out_size; (void)ws_size;

    char* ws = (char*)d_ws;
    size_t o = 0;
    auto alloc = [&](size_t bytes) { size_t r = o; o += (bytes + 255) & ~(size_t)255; return r; };
    f16*   xpad   = (f16*)(ws + alloc((size_t)NB * TXP * CIN * 2));
    f16*   hbufA  = (f16*)(ws + alloc((size_t)NB * THP * DH * 2));
    f16*   hbufB  = (f16*)(ws + alloc((size_t)NB * THP * DH * 2));
    f16*   Hc     = (f16*)(ws + alloc((size_t)NU * NB * 1024 * 2));
    f16*   w0T    = (f16*)(ws + alloc((size_t)512 * 448 * 2));
    f16*   tcrT   = (f16*)(ws + alloc((size_t)4 * 512 * 2560 * 2));
    f16*   wrecT  = (f16*)(ws + alloc((size_t)1536 * 512 * 2));
    f16*   fcT    = (f16*)(ws + alloc((size_t)1024 * 1024 * 2));
    float* gsum   = (float*)(ws + alloc(80 * 4));
    float* gsumsq = (float*)(ws + alloc(80 * 4));
    int*   lcnt   = (int*)(ws + alloc(64));
    int*   gflag  = (int*)(ws + alloc(256));   // own cacheline: GRU flag stores never contend with lcnt atomics

    init_zero<<<64, 256, 0, stream>>>(gsum, gsumsq, lcnt, gflag, xpad, hbufA, hbufB, Hc);
    transpose_f32_f16<<<dim3(16, 14), 256, 0, stream>>>(w0, 400, 512, w0T, 512, 448);
    for (int i = 0; i < 4; i++)
        transpose_f32_f16<<<dim3(16, 80), 256, 0, stream>>>(tcrw + (size_t)i * 2560 * 512, 2560, 512,
                                                            tcrT + (size_t)i * 512 * 2560, 512, 2560);
    transpose_f32_f16<<<dim3(48, 16), 256, 0, stream>>>(grk, 512, 1536, wrecT, 1536, 512);
    transpose_f32_f16<<<dim3(32, 32), 256, 0, stream>>>(fcw, 1024, 1000, fcT, 1024, 1024);

    bn_stats<<<256, 256, 0, stream>>>(x, gsum, gsumsq);
    bn_apply<<<16000, 256, 0, stream>>>(x, gsum, gsumsq, gamma, beta, xpad);

    // mega-kernel: GRU + encoder + flag-gated streaming decode
    enc_gru<<<8 + EWG, 256, 0, stream>>>(wrecT, gk, gbias, ytrue, Hc,
                                         xpad, w0T, b0, tcrT, tcrb, hbufA, hbufB,
                                         lcnt, gflag, fcT, fcb, out);

    // final softmax over logits
    row_softmax<<<6400, 256, 0, stream>>>(out, 1000);
}

// Round 14
// 1729.249 us; speedup vs baseline: 1.0499x; 1.0499x over previous
//
#include <hip/hip_runtime.h>
#include <cstdint>

typedef _Float16 f16;
typedef __attribute__((ext_vector_type(2))) _Float16 f16x2;
typedef __attribute__((ext_vector_type(8))) _Float16 f16x8;
typedef __attribute__((ext_vector_type(4))) float f32x4;
typedef __attribute__((ext_vector_type(2))) float f32x2;
typedef __attribute__((ext_vector_type(8))) unsigned short us8;   // 16 B — staging vector
typedef __attribute__((ext_vector_type(4))) int i32x4;

#define NB   32
#define TIN  1600
#define CIN  80
#define TOUT 800
#define DH   512
#define NV   1000
#define NU   200
#define TXP  1604   // xpad time rows (1 left pad + 1600 + 3 tail)
#define THP  804    // conv buffer time rows (2 pad each side)
#define EPSB 1e-3f
#define EWG  248    // encoder worker blocks in the fused kernel (8+248 = 256 = #CUs)

// ---- stores ----
// L2-local write-through (same-XCD exchange): sc0 only — CDNA vector L1 is
// write-through, so the store lands in the XCD-shared L2 (the fast coherence point
// when producer+consumer are co-located on one XCD).
__device__ __forceinline__ void st_l2_f16(f16* p, float v)
{
    f16 h = (f16)v;
    short s; __builtin_memcpy(&s, &h, 2);
    int si = (int)s;
    asm volatile("global_store_short %0, %1, off sc0"
                 :: "v"(p), "v"(si) : "memory");
}

// ---- 16-load fragment blobs (one h-batch = 16 x dwordx4 = row segments for MFMA) ----
__device__ __forceinline__ void load16_sc0(const f16* base, f16x8 v[16])
{
    asm volatile(
        "global_load_dwordx4 %0, %16, off sc0\n\t"
        "global_load_dwordx4 %1, %16, off offset:64 sc0\n\t"
        "global_load_dwordx4 %2, %16, off offset:128 sc0\n\t"
        "global_load_dwordx4 %3, %16, off offset:192 sc0\n\t"
        "global_load_dwordx4 %4, %16, off offset:256 sc0\n\t"
        "global_load_dwordx4 %5, %16, off offset:320 sc0\n\t"
        "global_load_dwordx4 %6, %16, off offset:384 sc0\n\t"
        "global_load_dwordx4 %7, %16, off offset:448 sc0\n\t"
        "global_load_dwordx4 %8, %16, off offset:512 sc0\n\t"
        "global_load_dwordx4 %9, %16, off offset:576 sc0\n\t"
        "global_load_dwordx4 %10, %16, off offset:640 sc0\n\t"
        "global_load_dwordx4 %11, %16, off offset:704 sc0\n\t"
        "global_load_dwordx4 %12, %16, off offset:768 sc0\n\t"
        "global_load_dwordx4 %13, %16, off offset:832 sc0\n\t"
        "global_load_dwordx4 %14, %16, off offset:896 sc0\n\t"
        "global_load_dwordx4 %15, %16, off offset:960 sc0\n\t"
        "s_waitcnt vmcnt(0)"
        : "=&v"(v[0]), "=&v"(v[1]), "=&v"(v[2]), "=&v"(v[3]),
          "=&v"(v[4]), "=&v"(v[5]), "=&v"(v[6]), "=&v"(v[7]),
          "=&v"(v[8]), "=&v"(v[9]), "=&v"(v[10]), "=&v"(v[11]),
          "=&v"(v[12]), "=&v"(v[13]), "=&v"(v[14]), "=&v"(v[15])
        : "v"(base)
        : "memory");
}
__device__ __forceinline__ void load16_sc1(const f16* base, f16x8 v[16])
{
    asm volatile(
        "global_load_dwordx4 %0, %16, off sc1\n\t"
        "global_load_dwordx4 %1, %16, off offset:64 sc1\n\t"
        "global_load_dwordx4 %2, %16, off offset:128 sc1\n\t"
        "global_load_dwordx4 %3, %16, off offset:192 sc1\n\t"
        "global_load_dwordx4 %4, %16, off offset:256 sc1\n\t"
        "global_load_dwordx4 %5, %16, off offset:320 sc1\n\t"
        "global_load_dwordx4 %6, %16, off offset:384 sc1\n\t"
        "global_load_dwordx4 %7, %16, off offset:448 sc1\n\t"
        "global_load_dwordx4 %8, %16, off offset:512 sc1\n\t"
        "global_load_dwordx4 %9, %16, off offset:576 sc1\n\t"
        "global_load_dwordx4 %10, %16, off offset:640 sc1\n\t"
        "global_load_dwordx4 %11, %16, off offset:704 sc1\n\t"
        "global_load_dwordx4 %12, %16, off offset:768 sc1\n\t"
        "global_load_dwordx4 %13, %16, off offset:832 sc1\n\t"
        "global_load_dwordx4 %14, %16, off offset:896 sc1\n\t"
        "global_load_dwordx4 %15, %16, off offset:960 sc1\n\t"
        "s_waitcnt vmcnt(0)"
        : "=&v"(v[0]), "=&v"(v[1]), "=&v"(v[2]), "=&v"(v[3]),
          "=&v"(v[4]), "=&v"(v[5]), "=&v"(v[6]), "=&v"(v[7]),
          "=&v"(v[8]), "=&v"(v[9]), "=&v"(v[10]), "=&v"(v[11]),
          "=&v"(v[12]), "=&v"(v[13]), "=&v"(v[14]), "=&v"(v[15])
        : "v"(base)
        : "memory");
}

// NaN-propagating validity check (R4-proven): true iff no 0x7FFF poison half present.
__device__ __forceinline__ bool h16_ok(const f16x8 v[16])
{
    f16x8 s0 = v[0] + v[1],   s1 = v[2] + v[3];
    f16x8 s2 = v[4] + v[5],   s3 = v[6] + v[7];
    f16x8 s4 = v[8] + v[9],   s5 = v[10] + v[11];
    f16x8 s6 = v[12] + v[13], s7 = v[14] + v[15];
    s0 += s1; s2 += s3; s4 += s5; s6 += s7;
    s0 += s2; s4 += s6; s0 += s4;
    float r = (float)s0[0] + (float)s0[1] + (float)s0[2] + (float)s0[3]
            + (float)s0[4] + (float)s0[5] + (float)s0[6] + (float)s0[7];
    return !__any(r != r);
}

// Same-XCD fast poll with correctness-preserving escalation:
//  mode 0: poll via sc0 (L2-local, ~200cy). Every 64 failed tries, ONE sc1 probe;
//          if sc1 sees data that sc0 just missed -> sc0 is blind -> sticky escalate.
//  mode 1: R8-proven sc1 (system) poll — guaranteed-correct fallback (same-XCD dirty
//          L2 lines are served to system-scope loads by ownership).
__device__ __forceinline__ void poll_l2(const f16* base, f16x8 v[16], int& mode)
{
    if (mode == 0) {
        while (true) {
            for (int i = 0; i < 64; i++) {
                load16_sc0(base, v);
                if (h16_ok(v)) return;
                __builtin_amdgcn_s_sleep(1);
            }
            load16_sc1(base, v);
            if (h16_ok(v)) { mode = 1; return; }   // sc0 blind -> permanent fallback
            __builtin_amdgcn_s_sleep(1);
        }
    }
    while (true) {
        load16_sc1(base, v);
        if (h16_ok(v)) return;
        __builtin_amdgcn_s_sleep(1);
    }
}

__device__ __forceinline__ float fast_tanh(float x)
{
    return 1.f - 2.f / (__expf(2.f * x) + 1.f);
}

// ---------------------------------------------------------------- init
__global__ void init_zero(float* gsum, float* gsumsq,
                          int* lcnt, f16* xpad, f16* hbufA, f16* hbufB,
                          f16* Hc)
{
    int tid = blockIdx.x * 256 + threadIdx.x;
    int stride = gridDim.x * 256;
    if (blockIdx.x == 0) {
        if (threadIdx.x < 80) { gsum[threadIdx.x] = 0.f; gsumsq[threadIdx.x] = 0.f; }
        if (threadIdx.x >= 128 && threadIdx.x < 144) lcnt[threadIdx.x - 128] = 0;
    }
    // xpad zero rows: t'=0, 1601..1603 per b
    for (int i = tid; i < NB * 4 * CIN; i += stride) {
        int b = i / (4 * CIN), rr = (i / CIN) % 4, c = i % CIN;
        int row = (rr == 0) ? 0 : (1600 + rr);
        xpad[((long)b * TXP + row) * CIN + c] = (f16)0.f;
    }
    // hbuf zero rows: t'=0,1,802,803 per b, both buffers
    for (int i = tid; i < 2 * NB * 4 * DH; i += stride) {
        int q = i; int buf = q / (NB * 4 * DH); q %= NB * 4 * DH;
        int b = q / (4 * DH); int rr = (q / DH) % 4; int dd = q % DH;
        int row = (rr < 2) ? rr : (800 + rr);
        f16* hb = buf ? hbufB : hbufA;
        hb[((long)b * THP + row) * DH + dd] = (f16)0.f;
    }
    // Hc h-region NaN poison (cols 0..511 of all 6400 rows) for the sentinel protocol
    us8 sent;
#pragma unroll
    for (int e = 0; e < 8; e++) sent[e] = 0x7FFFu;
    for (int i = tid; i < 6400 * 64; i += stride)
        *(us8*)&Hc[(long)(i >> 6) * 1024 + (i & 63) * 8] = sent;
}

// ---------------------------------------------------------------- transpose f32 -> f16 (out[c][r] = in[r][c], OOB -> 0)
__global__ void transpose_f32_f16(const float* __restrict__ in, int R, int C,
                                  f16* __restrict__ out, int outRows, int outCols)
{
    __shared__ float t[32][33];
    int c0 = blockIdx.x * 32, r0 = blockIdx.y * 32;
    int x = threadIdx.x & 31, y = threadIdx.x >> 5;
    for (int i = y; i < 32; i += 8) {
        int r = r0 + i, c = c0 + x;
        t[i][x] = (r < R && c < C) ? in[(long)r * C + c] : 0.0f;
    }
    __syncthreads();
    for (int i = y; i < 32; i += 8) {
        int orow = c0 + i, ocol = r0 + x;
        if (orow < outRows && ocol < outCols)
            out[(long)orow * outCols + ocol] = (f16)t[x][i];
    }
}

// ---------------------------------------------------------------- batchnorm
__global__ void bn_stats(const float* __restrict__ x, float* gsum, float* gsumsq)
{
    __shared__ float ls[240], ls2[240];
    const float* base = x + (long)blockIdx.x * 200 * CIN;
    int tid = threadIdx.x;
    if (tid < 240) {
        int c = tid % 80, rg = tid / 80;
        float s = 0.f, s2 = 0.f;
        for (int r = rg; r < 200; r += 3) {
            float v = base[r * CIN + c];
            s += v; s2 += v * v;
        }
        ls[tid] = s; ls2[tid] = s2;
    }
    __syncthreads();
    if (tid < 80) {
        atomicAdd(&gsum[tid],   ls[tid] + ls[tid + 80] + ls[tid + 160]);
        atomicAdd(&gsumsq[tid], ls2[tid] + ls2[tid + 80] + ls2[tid + 160]);
    }
}

__global__ void bn_apply(const float* __restrict__ x, const float* __restrict__ gsum,
                         const float* __restrict__ gsumsq, const float* __restrict__ gamma,
                         const float* __restrict__ beta, f16* __restrict__ xpad)
{
    long idx = (long)blockIdx.x * 256 + threadIdx.x;
    if (idx >= (long)NB * TIN * CIN) return;
    int c = (int)(idx % CIN);
    long bt = idx / CIN;
    int t = (int)(bt % TIN); int b = (int)(bt / TIN);
    float mean = gsum[c] * (1.f / 51200.f);
    float var  = gsumsq[c] * (1.f / 51200.f) - mean * mean;
    float sc = gamma[c] * rsqrtf(var + EPSB);
    float sh = beta[c] - mean * sc;
    xpad[((long)b * TXP + t + 1) * CIN + c] = (f16)(x[idx] * sc + sh);
}

// ---------------------------------------------------------------- generic fp16 MFMA GEMM (64x128 tile) — tail use only
// MODE 2: attention scores (f32)   MODE 3: fc (bias -> f32 logits in d_out)
template<int MODE>
__launch_bounds__(256)
__global__ void gemm16(const f16* __restrict__ Ab, long strideA, long slabA,
                       const f16* __restrict__ Bb, long strideB, long slabB,
                       int M, int N, int Kchunks,
                       const float* __restrict__ bias,
                       float* __restrict__ outF)
{
    __shared__ f16 As[64][72];
    __shared__ f16 Bs[128][72];
    const int b = blockIdx.z;
    const f16* Abase = Ab + (long)b * slabA;
    const f16* Bbase = Bb + (long)b * slabB;
    const int m0 = blockIdx.x * 64, n0 = blockIdx.y * 128;
    const int tid = threadIdx.x;
    const int lane = tid & 63, wv = tid >> 6;
    const int lm = lane & 15, lk = lane >> 4;

    f32x4 vzero = {0.f, 0.f, 0.f, 0.f};
    f32x4 acc[4][2];
#pragma unroll
    for (int i = 0; i < 4; i++) { acc[i][0] = vzero; acc[i][1] = vzero; }

    const int srow = tid >> 3, scol = (tid & 7) * 8;

    for (int kc = 0; kc < Kchunks; kc++) {
        int kb = kc * 64;
#pragma unroll
        for (int p = 0; p < 2; p++) {
            int r = srow + p * 32;
            int m = m0 + r; if (m > M - 1) m = M - 1;
            *(us8*)&As[r][scol] = *(const us8*)(Abase + (long)m * strideA + kb + scol);
        }
#pragma unroll
        for (int p = 0; p < 4; p++) {
            int r = srow + p * 32;
            int n = n0 + r; if (n > N - 1) n = N - 1;
            *(us8*)&Bs[r][scol] = *(const us8*)(Bbase + (long)n * strideB + kb + scol);
        }
        __syncthreads();
#pragma unroll
        for (int ks = 0; ks < 2; ks++) {
            f16x8 af[4], bf[2];
#pragma unroll
            for (int mt = 0; mt < 4; mt++)
                af[mt] = *(const f16x8*)&As[mt * 16 + lm][ks * 32 + lk * 8];
#pragma unroll
            for (int nt = 0; nt < 2; nt++)
                bf[nt] = *(const f16x8*)&Bs[wv * 32 + nt * 16 + lm][ks * 32 + lk * 8];
#pragma unroll
            for (int mt = 0; mt < 4; mt++)
#pragma unroll
                for (int nt = 0; nt < 2; nt++)
                    acc[mt][nt] = __builtin_amdgcn_mfma_f32_16x16x32_f16(af[mt], bf[nt], acc[mt][nt], 0, 0, 0);
        }
        __syncthreads();
    }
#pragma unroll
    for (int mt = 0; mt < 4; mt++) {
#pragma unroll
        for (int nt = 0; nt < 2; nt++) {
            int n = n0 + wv * 32 + nt * 16 + lm;
#pragma unroll
            for (int reg = 0; reg < 4; reg++) {
                int m = m0 + mt * 16 + lk * 4 + reg;
                if (m >= M || n >= N) continue;
                float v = acc[mt][nt][reg];
                if (MODE == 2) {
                    outF[((long)b * NU + m) * 800 + n] = v;
                } else {
                    v += bias[n];
                    int u = m >> 5, bb = m & 31;
                    outF[((long)bb * NU + u) * 1000 + n] = v;
                }
            }
        }
    }
}

// ---------------------------------------------------------------- encoder layer worker (inside fused kernel)
// One layer = 1664 tiles (32 batches x 13 Mtiles x 4 Ntiles), M=800, N=512.
__device__ void enc_layer(int eb, int tid,
                          const f16* __restrict__ Ab, long strideA, long slabA,
                          const f16* __restrict__ Bb, long strideB,
                          int Kchunks, const float* __restrict__ bias,
                          const f16* __restrict__ resid, f16* __restrict__ outH,
                          long slabRO, f16 As[][72], f16 Bs[][72])
{
    const int lane = tid & 63, wv = tid >> 6;
    const int lm = lane & 15, lk = lane >> 4;
    const int srow = tid >> 3, scol = (tid & 7) * 8;
    f32x4 vzero = {0.f, 0.f, 0.f, 0.f};

    for (int t = eb; t < 1664; t += EWG) {
        int b = t / 52, rem = t - b * 52;
        int m0 = (rem >> 2) * 64, n0 = (rem & 3) * 128;
        const f16* Abase = Ab + (long)b * slabA;

        f32x4 acc[4][2];
#pragma unroll
        for (int i = 0; i < 4; i++) { acc[i][0] = vzero; acc[i][1] = vzero; }

        for (int kc = 0; kc < Kchunks; kc++) {
            int kb = kc * 64;
#pragma unroll
            for (int p = 0; p < 2; p++) {
                int r = srow + p * 32;
                int m = m0 + r; if (m > 799) m = 799;
                *(us8*)&As[r][scol] = *(const us8*)(Abase + (long)m * strideA + kb + scol);
            }
#pragma unroll
            for (int p = 0; p < 4; p++) {
                int r = srow + p * 32;
                *(us8*)&Bs[r][scol] = *(const us8*)(Bb + (long)(n0 + r) * strideB + kb + scol);
            }
            __syncthreads();
#pragma unroll
            for (int ks = 0; ks < 2; ks++) {
                f16x8 af[4], bf[2];
#pragma unroll
                for (int mt = 0; mt < 4; mt++)
                    af[mt] = *(const f16x8*)&As[mt * 16 + lm][ks * 32 + lk * 8];
#pragma unroll
                for (int nt = 0; nt < 2; nt++)
                    bf[nt] = *(const f16x8*)&Bs[wv * 32 + nt * 16 + lm][ks * 32 + lk * 8];
#pragma unroll
                for (int mt = 0; mt < 4; mt++)
#pragma unroll
                    for (int nt = 0; nt < 2; nt++)
                        acc[mt][nt] = __builtin_amdgcn_mfma_f32_16x16x32_f16(af[mt], bf[nt], acc[mt][nt], 0, 0, 0);
            }
            __syncthreads();
        }
#pragma unroll
        for (int mt = 0; mt < 4; mt++) {
#pragma unroll
            for (int nt = 0; nt < 2; nt++) {
                int n = n0 + wv * 32 + nt * 16 + lm;
#pragma unroll
                for (int reg = 0; reg < 4; reg++) {
                    int m = m0 + mt * 16 + lk * 4 + reg;
                    if (m >= 800) continue;
                    float v = acc[mt][nt][reg] + bias[n];
                    v = v > 0.f ? v : 0.f;
                    if (resid) v += (float)resid[(long)b * slabRO + (long)(2 + m) * DH + n];
                    outH[(long)b * slabRO + (long)(2 + m) * DH + n] = (f16)v;
                }
            }
        }
    }
}

// ---------------------------------------------------------------- fused: XCD-registered roles.
// All 256 blocks read HW_REG_XCC_ID, register per-XCD, grid-barrier, then the first 8
// blocks on the first XCD with >=8 blocks become GRU blocks (their h-exchange runs
// through that XCD's SHARED L2 via sc0 stores/loads — ~200cy vs ~800cy L3). Everyone
// else claims an encoder-worker ticket 0..247. GRU math is R8-verbatim.
__launch_bounds__(256, 1)
__global__ void enc_gru(const f16* __restrict__ wrecT, const float* __restrict__ gk,
                        const float* __restrict__ gbias, const int* __restrict__ ytrue,
                        f16* __restrict__ Hc,
                        const f16* __restrict__ xpad, const f16* __restrict__ w0T,
                        const float* __restrict__ b0, const f16* __restrict__ tcrT,
                        const float* __restrict__ tcrb,
                        f16* __restrict__ hbufA, f16* __restrict__ hbufB,
                        int* __restrict__ lcnt)
{
    const int tid = threadIdx.x;

    // ---- XCD registration (lcnt[5]=regcount, lcnt[6]=worker ticket, lcnt[8..15]=per-XCD counts) ----
    __shared__ int sRole, sWid;
    if (tid == 0) {
        unsigned int xcd;
        asm volatile("s_getreg_b32 %0, hwreg(HW_REG_XCC_ID)" : "=s"(xcd));
        xcd &= 7;
        int slot = __hip_atomic_fetch_add(&lcnt[8 + xcd], 1, __ATOMIC_RELAXED, __HIP_MEMORY_SCOPE_AGENT);
        __hip_atomic_fetch_add(&lcnt[5], 1, __ATOMIC_RELEASE, __HIP_MEMORY_SCOPE_AGENT);
        while (__hip_atomic_load(&lcnt[5], __ATOMIC_RELAXED, __HIP_MEMORY_SCOPE_AGENT) < 8 + EWG)
            __builtin_amdgcn_s_sleep(2);
        (void)__hip_atomic_load(&lcnt[5], __ATOMIC_ACQUIRE, __HIP_MEMORY_SCOPE_AGENT);
        int target = 0;
        for (int x = 0; x < 8; x++) {
            int c = __hip_atomic_load(&lcnt[8 + x], __ATOMIC_RELAXED, __HIP_MEMORY_SCOPE_AGENT);
            if (c >= 8) { target = x; break; }   // pigeonhole: exists (256 blocks / 8 XCDs)
        }
        if ((int)xcd == target && slot < 8) { sRole = slot; sWid = 0; }
        else { sRole = -1; sWid = __hip_atomic_fetch_add(&lcnt[6], 1, __ATOMIC_RELAXED, __HIP_MEMORY_SCOPE_AGENT); }
    }
    __syncthreads();
    const int role = sRole, wid = sWid;

    if (role >= 0) {
        // ==================== GRU (R8 math verbatim; L2-local exchange) ====================
        __shared__ int yl[NU * 32];
        const int lane = tid & 63, wv = tid >> 6;
        const int gw = role * 4 + wv;
        const int lm = lane & 15, lk = lane >> 4;
        const int j = gw * 16 + lm;

        for (int i = tid; i < NU * 32; i += 256) {
            int b = i / NU, u = i - b * NU;
            yl[u * 32 + b] = ytrue[b * 201 + u];
        }

        f16x8 wf[3][16];
#pragma unroll
        for (int g = 0; g < 3; g++)
#pragma unroll
            for (int ks = 0; ks < 16; ks++) {
                wf[g][ks] = *(const f16x8*)&wrecT[(long)(g * 512 + j) * 512 + ks * 32 + lk * 8];
                asm volatile("" : "+v"(wf[g][ks]));
            }

        const float biz = gbias[j],        bir = gbias[512 + j],        bic = gbias[1024 + j];
        const float brz = gbias[1536 + j], brr = gbias[1536 + 512 + j], brc = gbias[1536 + 1024 + j];
        f32x4 vzero = {0.f, 0.f, 0.f, 0.f};

        __syncthreads();

        float hold[8];
        float nxz[8], nxr[8], nxh[8], mxz[8], mxr[8], mxh[8];
#pragma unroll
        for (int s = 0; s < 8; s++) {
            hold[s] = 0.f;
            int b = ((s >> 2) << 4) + lk * 4 + (s & 3);
            const float* gkr = gk + (long)yl[b] * 1536;
            nxz[s] = gkr[j]; nxr[s] = gkr[512 + j]; nxh[s] = gkr[1024 + j];
        }

        int mode = 0;   // 0 = sc0/L2-local poll; sticky-escalates to sc1 if sc0 proves blind
        for (int u = 0; u < NU; u++) {
            int up = (u < NU - 1) ? u + 1 : u;
#pragma unroll
            for (int s = 0; s < 8; s++) {
                int b = ((s >> 2) << 4) + lk * 4 + (s & 3);
                const float* gkr = gk + (long)yl[up * 32 + b] * 1536;
                mxz[s] = gkr[j]; mxr[s] = gkr[512 + j]; mxh[s] = gkr[1024 + j];
            }

            f32x4 acc[3][2];
#pragma unroll
            for (int g = 0; g < 3; g++) { acc[g][0] = vzero; acc[g][1] = vzero; }

            if (u > 0) {
                const f16* baseA = Hc + ((long)(u - 1) * 32 + lm) * 1024 + lk * 8;
                // batch A: rows lm (batches 0..15) — consume fully before loading batch B
                {
                    f16x8 va[16];
                    poll_l2(baseA, va, mode);
#pragma unroll
                    for (int ks = 0; ks < 16; ks++)
#pragma unroll
                        for (int g = 0; g < 3; g++)
                            acc[g][0] = __builtin_amdgcn_mfma_f32_16x16x32_f16(va[ks], wf[g][ks], acc[g][0], 0, 0, 0);
                }
                // batch B: rows 16+lm (batches 16..31)
                {
                    f16x8 vb[16];
                    poll_l2(baseA + 16 * 1024, vb, mode);
#pragma unroll
                    for (int ks = 0; ks < 16; ks++)
#pragma unroll
                        for (int g = 0; g < 3; g++)
                            acc[g][1] = __builtin_amdgcn_mfma_f32_16x16x32_f16(vb[ks], wf[g][ks], acc[g][1], 0, 0, 0);
                }
            }

#pragma unroll
            for (int mt = 0; mt < 2; mt++) {
#pragma unroll
                for (int reg = 0; reg < 4; reg++) {
                    int s = mt * 4 + reg;
                    int b = mt * 16 + lk * 4 + reg;
                    float hz = acc[0][mt][reg] + brz;
                    float hr = acc[1][mt][reg] + brr;
                    float hh = acc[2][mt][reg] + brc;
                    float z = 1.f / (1.f + __expf(-(nxz[s] + biz + hz)));
                    float r = 1.f / (1.f + __expf(-(nxr[s] + bir + hr)));
                    float cd = fast_tanh(nxh[s] + bic + r * hh);
                    float hnew = z * hold[s] + (1.f - z) * cd;
                    hold[s] = hnew;
                    st_l2_f16(&Hc[((long)u * 32 + b) * 1024 + j], hnew);   // sc0: stays in shared L2
                }
            }
#pragma unroll
            for (int s = 0; s < 8; s++) { nxz[s] = mxz[s]; nxr[s] = mxr[s]; nxh[s] = mxh[s]; }
            // no flag, no drain, no barrier: readers gate on the data itself
        }
        asm volatile("s_waitcnt vmcnt(0)" ::: "memory");
        // kernel-end implicit writeback publishes Hc (L2 dirty lines) to later dispatches
        return;
    }

    // ==================== encoder workers ====================
    __shared__ f16 As[64][72];
    __shared__ f16 Bs[128][72];
    const int eb = wid;   // 0..247

    // layer 0: conv0
    enc_layer(eb, tid, xpad, 160, (long)TXP * CIN, w0T, 448, 7, b0,
              nullptr, hbufA, (long)THP * DH, As, Bs);

    const f16* tin = hbufA; f16* tout = hbufB;
    for (int L = 0; L < 4; L++) {
        // barrier: publish layer L-output (release), wait all, invalidate (acquire)
        __syncthreads();
        if (tid == 0) {
            __hip_atomic_fetch_add(&lcnt[L], 1, __ATOMIC_RELEASE, __HIP_MEMORY_SCOPE_AGENT);
            while (__hip_atomic_load(&lcnt[L], __ATOMIC_RELAXED, __HIP_MEMORY_SCOPE_AGENT) < EWG)
                __builtin_amdgcn_s_sleep(8);
            (void)__hip_atomic_load(&lcnt[L], __ATOMIC_ACQUIRE, __HIP_MEMORY_SCOPE_AGENT);
        }
        __syncthreads();

        enc_layer(eb, tid, tin, 512, (long)THP * DH, tcrT + (size_t)L * 512 * 2560, 2560,
                  40, tcrb + L * 512, tin, tout, (long)THP * DH, As, Bs);
        const f16* t2 = tout; tout = (f16*)tin; tin = t2;
    }
    // final output in hbufA; kernel-end flush publishes it to later dispatches
}

// ---------------------------------------------------------------- row softmax in place (len <= 1024) — final output only
__global__ void row_softmax(float* __restrict__ base, int len)
{
    float* s = base + (long)blockIdx.x * len;
    int tid = threadIdx.x;
    float v[4]; float mx = -1e30f;
#pragma unroll
    for (int i = 0; i < 4; i++) {
        int idx = tid + i * 256;
        v[i] = (idx < len) ? s[idx] : -1e30f;
        mx = fmaxf(mx, v[i]);
    }
#pragma unroll
    for (int off = 32; off; off >>= 1) mx = fmaxf(mx, __shfl_xor(mx, off));
    __shared__ float red[4], red2[4];
    if ((tid & 63) == 0) red[tid >> 6] = mx;
    __syncthreads();
    mx = fmaxf(fmaxf(red[0], red[1]), fmaxf(red[2], red[3]));
    float sum = 0.f;
#pragma unroll
    for (int i = 0; i < 4; i++) { v[i] = __expf(v[i] - mx); sum += v[i]; }
#pragma unroll
    for (int off = 32; off; off >>= 1) sum += __shfl_xor(sum, off);
    if ((tid & 63) == 0) red2[tid >> 6] = sum;
    __syncthreads();
    sum = red2[0] + red2[1] + red2[2] + red2[3];
    float inv = 1.f / sum;
#pragma unroll
    for (int i = 0; i < 4; i++) {
        int idx = tid + i * 256;
        if (idx < len) s[idx] = v[i] * inv;
    }
}

// ---------------------------------------------------------------- ctx with FUSED softmax (R6/R8-validated): reads RAW
// scores, softmaxes each row (identical FP op order to row_softmax -> bit-identical alpha), then ctx = alpha @ enc.
__global__ void ctx_kernel(const float* __restrict__ scores, const f16* __restrict__ enc,
                           f16* __restrict__ Hc)
{
    __shared__ float al[800][18];
    __shared__ float red[4], red2[4];
    int b = blockIdx.x, ut = blockIdx.y;
    int u0 = ut * 16;
    int tid = threadIdx.x;
    for (int ul = 0; ul < 16; ul++) {
        int u = u0 + ul;
        if (u < NU) {
            const float* arow = scores + ((long)b * NU + u) * 800;
            float v[4]; float mx = -1e30f;
#pragma unroll
            for (int i = 0; i < 4; i++) {
                int idx = tid + i * 256;
                v[i] = (idx < 800) ? arow[idx] : -1e30f;
                mx = fmaxf(mx, v[i]);
            }
#pragma unroll
            for (int off = 32; off; off >>= 1) mx = fmaxf(mx, __shfl_xor(mx, off));
            if ((tid & 63) == 0) red[tid >> 6] = mx;
            __syncthreads();
            mx = fmaxf(fmaxf(red[0], red[1]), fmaxf(red[2], red[3]));
            float sum = 0.f;
#pragma unroll
            for (int i = 0; i < 4; i++) { v[i] = __expf(v[i] - mx); sum += v[i]; }
#pragma unroll
            for (int off = 32; off; off >>= 1) sum += __shfl_xor(sum, off);
            if ((tid & 63) == 0) red2[tid >> 6] = sum;
            __syncthreads();
            sum = red2[0] + red2[1] + red2[2] + red2[3];
            float inv = 1.f / sum;
#pragma unroll
            for (int i = 0; i < 4; i++) {
                int idx = tid + i * 256;
                if (idx < 800) al[idx][ul] = v[i] * inv;
            }
            __syncthreads();   // red/red2 reuse safety (uniform branch: u depends only on blockIdx/ul)
        } else {
            for (int t = tid; t < 800; t += 256) al[t][ul] = 0.f;
        }
    }
    __syncthreads();
    int d0 = tid * 2;
    float a0[16], a1[16];
#pragma unroll
    for (int i = 0; i < 16; i++) { a0[i] = 0.f; a1[i] = 0.f; }
    const f16* encb = enc + ((long)b * THP + 2) * DH + d0;
    for (int t = 0; t < 800; t++) {
        f16x2 e = *(const f16x2*)&encb[(long)t * DH];
        float f0 = (float)e.x, f1 = (float)e.y;
#pragma unroll
        for (int g = 0; g < 8; g++) {
            f32x2 ap = *(const f32x2*)&al[t][2 * g];
            a0[2 * g]     += ap.x * f0; a0[2 * g + 1] += ap.y * f0;
            a1[2 * g]     += ap.x * f1; a1[2 * g + 1] += ap.y * f1;
        }
    }
#pragma unroll
    for (int ul = 0; ul < 16; ul++) {
        int u = u0 + ul;
        if (u < NU) {
            Hc[((long)u * 32 + b) * 1024 + 512 + d0]     = (f16)a0[ul];
            Hc[((long)u * 32 + b) * 1024 + 512 + d0 + 1] = (f16)a1[ul];
        }
    }
}

// ---------------------------------------------------------------- launcher
extern "C" void kernel_launch(void* const* d_in, const int* in_sizes, int n_in,
                              void* d_out, int out_size, void* d_ws, size_t ws_size,
                              hipStream_t stream)
{
    const float* x     = (const float*)d_in[0];
    const int*   ytrue = (const int*)d_in[1];
    const float* gamma = (const float*)d_in[2];
    const float* beta  = (const float*)d_in[3];
    const float* w0    = (const float*)d_in[4];
    const float* b0    = (const float*)d_in[5];
    const float* tcrw  = (const float*)d_in[6];
    const float* tcrb  = (const float*)d_in[7];
    const float* gk    = (const float*)d_in[8];
    const float* grk   = (const float*)d_in[9];
    const float* gbias = (const float*)d_in[10];
    const float* fcw   = (const float*)d_in[11];
    const float* fcb   = (const float*)d_in[12];
    float* out = (float*)d_out;
    (void)in_sizes; (void)n_in; (void)out_size; (void)ws_size;

    char* ws = (char*)d_ws;
    size_t o = 0;
    auto alloc = [&](size_t bytes) { size_t r = o; o += (bytes + 255) & ~(size_t)255; return r; };
    f16*   xpad   = (f16*)(ws + alloc((size_t)NB * TXP * CIN * 2));
    f16*   hbufA  = (f16*)(ws + alloc((size_t)NB * THP * DH * 2));
    f16*   hbufB  = (f16*)(ws + alloc((size_t)NB * THP * DH * 2));
    f16*   Hc     = (f16*)(ws + alloc((size_t)NU * NB * 1024 * 2));
    float* scores = (float*)(ws + alloc((size_t)NB * NU * 800 * 4));
    f16*   w0T    = (f16*)(ws + alloc((size_t)512 * 448 * 2));
    f16*   tcrT   = (f16*)(ws + alloc((size_t)4 * 512 * 2560 * 2));
    f16*   wrecT  = (f16*)(ws + alloc((size_t)1536 * 512 * 2));
    f16*   fcT    = (f16*)(ws + alloc((size_t)1024 * 1024 * 2));
    float* gsum   = (float*)(ws + alloc(80 * 4));
    float* gsumsq = (float*)(ws + alloc(80 * 4));
    int*   lcnt   = (int*)(ws + alloc(64));

    init_zero<<<64, 256, 0, stream>>>(gsum, gsumsq, lcnt, xpad, hbufA, hbufB, Hc);
    transpose_f32_f16<<<dim3(16, 14), 256, 0, stream>>>(w0, 400, 512, w0T, 512, 448);
    for (int i = 0; i < 4; i++)
        transpose_f32_f16<<<dim3(16, 80), 256, 0, stream>>>(tcrw + (size_t)i * 2560 * 512, 2560, 512,
                                                            tcrT + (size_t)i * 512 * 2560, 512, 2560);
    transpose_f32_f16<<<dim3(48, 16), 256, 0, stream>>>(grk, 512, 1536, wrecT, 1536, 512);
    transpose_f32_f16<<<dim3(32, 32), 256, 0, stream>>>(fcw, 1024, 1000, fcT, 1024, 1024);

    bn_stats<<<256, 256, 0, stream>>>(x, gsum, gsumsq);
    bn_apply<<<16000, 256, 0, stream>>>(x, gsum, gsumsq, gamma, beta, xpad);

    // fused: GRU (8 XCD-colocated blocks, L2-local exchange) + encoder conv chain
    enc_gru<<<8 + EWG, 256, 0, stream>>>(wrecT, gk, gbias, ytrue, Hc,
                                         xpad, w0T, b0, tcrT, tcrb, hbufA, hbufB, lcnt);
    const f16* enc = hbufA;   // after 4 ping-pong swaps

    // scores[b][u][t] = Hc[u][b][:512] . enc[b][t][:]  (raw logits; softmax fused into ctx)
    gemm16<2><<<dim3(4, 7, 32), 256, 0, stream>>>(Hc, 32 * 1024, 1024, enc + 2 * DH, 512, (long)THP * DH,
        200, 800, 8, nullptr, scores);
    ctx_kernel<<<dim3(32, 13), 256, 0, stream>>>(scores, enc, Hc);

    // logits[b][u][v] = Hc_row(u*32+b)[0:1024] @ fcT + fc_b  -> d_out
    gemm16<3><<<dim3(100, 8, 1), 256, 0, stream>>>(Hc, 1024, 0, fcT, 1024, 0,
        6400, 1000, 16, fcb, out);
    row_softmax<<<6400, 256, 0, stream>>>(out, 1000);
}

// Round 15
// 1633.991 us; speedup vs baseline: 1.1111x; 1.0583x over previous
//
#include <hip/hip_runtime.h>
#include <cstdint>

typedef _Float16 f16;
typedef __attribute__((ext_vector_type(2))) _Float16 f16x2;
typedef __attribute__((ext_vector_type(8))) _Float16 f16x8;
typedef __attribute__((ext_vector_type(4))) float f32x4;
typedef __attribute__((ext_vector_type(2))) float f32x2;
typedef __attribute__((ext_vector_type(8))) unsigned short us8;   // 16 B — staging vector
typedef __attribute__((ext_vector_type(4))) int i32x4;

#define NB   32
#define TIN  1600
#define CIN  80
#define TOUT 800
#define DH   512
#define NV   1000
#define NU   200
#define TXP  1604   // xpad time rows (1 left pad + 1600 + 3 tail)
#define THP  804    // conv buffer time rows (2 pad each side)
#define EPSB 1e-3f
#define EWG  248    // encoder worker blocks in the fused kernel (8+248 = 256 = #CUs)

// write-through (coherence-point) stores — R4/R8-proven
__device__ __forceinline__ void st_sys_f16(f16* p, float v)
{
    f16 h = (f16)v;
    short s; __builtin_memcpy(&s, &h, 2);
    int si = (int)s;
    asm volatile("global_store_short %0, %1, off sc0 sc1"
                 :: "v"(p), "v"(si) : "memory");
}

// Sentinel-gated fragment batch load (R4/R8-proven): 16 x dwordx4 (sc1, bypasses stale
// L2) from base + ks*64B. Retries until no f16 half equals the 0x7FFF NaN poison.
// 64 VGPRs live per call — two sequential calls stay under the 256 arch-VGPR cap.
// Falsified alternatives: merged 32-load (R6: VGPR spill, -900us), issue-early overlap
// (R9/R10: retry traffic), L2-local sc0 exchange (R14: loses the L3 push, -150us),
// streaming consumers (R12/R13: decode traffic inflates the GRU's serial latency).
__device__ __forceinline__ void poll_h16(const f16* base, f16x8 v[16])
{
    while (true) {
        asm volatile(
            "global_load_dwordx4 %0, %16, off sc1\n\t"
            "global_load_dwordx4 %1, %16, off offset:64 sc1\n\t"
            "global_load_dwordx4 %2, %16, off offset:128 sc1\n\t"
            "global_load_dwordx4 %3, %16, off offset:192 sc1\n\t"
            "global_load_dwordx4 %4, %16, off offset:256 sc1\n\t"
            "global_load_dwordx4 %5, %16, off offset:320 sc1\n\t"
            "global_load_dwordx4 %6, %16, off offset:384 sc1\n\t"
            "global_load_dwordx4 %7, %16, off offset:448 sc1\n\t"
            "global_load_dwordx4 %8, %16, off offset:512 sc1\n\t"
            "global_load_dwordx4 %9, %16, off offset:576 sc1\n\t"
            "global_load_dwordx4 %10, %16, off offset:640 sc1\n\t"
            "global_load_dwordx4 %11, %16, off offset:704 sc1\n\t"
            "global_load_dwordx4 %12, %16, off offset:768 sc1\n\t"
            "global_load_dwordx4 %13, %16, off offset:832 sc1\n\t"
            "global_load_dwordx4 %14, %16, off offset:896 sc1\n\t"
            "global_load_dwordx4 %15, %16, off offset:960 sc1\n\t"
            "s_waitcnt vmcnt(0)"
            : "=&v"(v[0]), "=&v"(v[1]), "=&v"(v[2]), "=&v"(v[3]),
              "=&v"(v[4]), "=&v"(v[5]), "=&v"(v[6]), "=&v"(v[7]),
              "=&v"(v[8]), "=&v"(v[9]), "=&v"(v[10]), "=&v"(v[11]),
              "=&v"(v[12]), "=&v"(v[13]), "=&v"(v[14]), "=&v"(v[15])
            : "v"(base)
            : "memory");
        f16x8 s0 = v[0] + v[1],   s1 = v[2] + v[3];
        f16x8 s2 = v[4] + v[5],   s3 = v[6] + v[7];
        f16x8 s4 = v[8] + v[9],   s5 = v[10] + v[11];
        f16x8 s6 = v[12] + v[13], s7 = v[14] + v[15];
        s0 += s1; s2 += s3; s4 += s5; s6 += s7;
        s0 += s2; s4 += s6; s0 += s4;
        float r = (float)s0[0] + (float)s0[1] + (float)s0[2] + (float)s0[3]
                + (float)s0[4] + (float)s0[5] + (float)s0[6] + (float)s0[7];
        if (!__any(r != r)) return;
        __builtin_amdgcn_s_sleep(1);
    }
}

__device__ __forceinline__ float fast_tanh(float x)
{
    return 1.f - 2.f / (__expf(2.f * x) + 1.f);
}

// ---------------------------------------------------------------- fused prep: init + all 6 weight transposes in ONE
// dispatch (block-range dispatch; all parts independent — stream order places prep before every consumer).
__device__ void transpose_tile(const float* __restrict__ in, int R, int C,
                               f16* __restrict__ out, int outRows, int outCols,
                               int bx, int by, int tid)
{
    __shared__ float t[32][33];
    int c0 = bx * 32, r0 = by * 32;
    int x = tid & 31, y = tid >> 5;
    for (int i = y; i < 32; i += 8) {
        int r = r0 + i, c = c0 + x;
        t[i][x] = (r < R && c < C) ? in[(long)r * C + c] : 0.0f;
    }
    __syncthreads();
    for (int i = y; i < 32; i += 8) {
        int orow = c0 + i, ocol = r0 + x;
        if (orow < outRows && ocol < outCols)
            out[(long)orow * outCols + ocol] = (f16)t[x][i];
    }
}

// grid = 64 (init) + 224 (w0) + 5120 (tcr x4) + 768 (grk) + 1024 (fcw) = 7200 blocks
__global__ void prep(float* gsum, float* gsumsq, int* lcnt,
                     f16* xpad, f16* hbufA, f16* hbufB, f16* Hc,
                     const float* __restrict__ w0, f16* w0T,
                     const float* __restrict__ tcrw, f16* tcrT,
                     const float* __restrict__ grk, f16* wrecT,
                     const float* __restrict__ fcw, f16* fcT)
{
    const int bid = (int)blockIdx.x, tid = threadIdx.x;
    if (bid < 64) {
        // ---- init (R8 init_zero body, stride fixed at 64 blocks) ----
        int gtid = bid * 256 + tid;
        const int stride = 64 * 256;
        if (bid == 0) {
            if (tid < 80) { gsum[tid] = 0.f; gsumsq[tid] = 0.f; }
            if (tid >= 128 && tid < 136) lcnt[tid - 128] = 0;
        }
        // xpad zero rows: t'=0, 1601..1603 per b
        for (int i = gtid; i < NB * 4 * CIN; i += stride) {
            int b = i / (4 * CIN), rr = (i / CIN) % 4, c = i % CIN;
            int row = (rr == 0) ? 0 : (1600 + rr);
            xpad[((long)b * TXP + row) * CIN + c] = (f16)0.f;
        }
        // hbuf zero rows: t'=0,1,802,803 per b, both buffers
        for (int i = gtid; i < 2 * NB * 4 * DH; i += stride) {
            int q = i; int buf = q / (NB * 4 * DH); q %= NB * 4 * DH;
            int b = q / (4 * DH); int rr = (q / DH) % 4; int dd = q % DH;
            int row = (rr < 2) ? rr : (800 + rr);
            f16* hb = buf ? hbufB : hbufA;
            hb[((long)b * THP + row) * DH + dd] = (f16)0.f;
        }
        // Hc h-region NaN poison (cols 0..511 of all 6400 rows) for the sentinel protocol
        us8 sent;
#pragma unroll
        for (int e = 0; e < 8; e++) sent[e] = 0x7FFFu;
        for (int i = gtid; i < 6400 * 64; i += stride)
            *(us8*)&Hc[(long)(i >> 6) * 1024 + (i & 63) * 8] = sent;
        return;
    }
    int idx = bid - 64;
    if (idx < 224) {                                  // w0: 400x512 -> 512x448, dim3(16,14)
        transpose_tile(w0, 400, 512, w0T, 512, 448, idx % 16, idx / 16, tid);
        return;
    }
    idx -= 224;
    if (idx < 5120) {                                 // tcr[i]: 2560x512 -> 512x2560, dim3(16,80) x4
        int i = idx / 1280, l = idx % 1280;
        transpose_tile(tcrw + (size_t)i * 2560 * 512, 2560, 512,
                       tcrT + (size_t)i * 512 * 2560, 512, 2560, l % 16, l / 16, tid);
        return;
    }
    idx -= 5120;
    if (idx < 768) {                                  // grk: 512x1536 -> 1536x512, dim3(48,16)
        transpose_tile(grk, 512, 1536, wrecT, 1536, 512, idx % 48, idx / 48, tid);
        return;
    }
    idx -= 768;                                       // fcw: 1024x1000 -> 1024x1024, dim3(32,32)
    transpose_tile(fcw, 1024, 1000, fcT, 1024, 1024, idx % 32, idx / 32, tid);
}

// ---------------------------------------------------------------- batchnorm
__global__ void bn_stats(const float* __restrict__ x, float* gsum, float* gsumsq)
{
    __shared__ float ls[240], ls2[240];
    const float* base = x + (long)blockIdx.x * 200 * CIN;
    int tid = threadIdx.x;
    if (tid < 240) {
        int c = tid % 80, rg = tid / 80;
        float s = 0.f, s2 = 0.f;
        for (int r = rg; r < 200; r += 3) {
            float v = base[r * CIN + c];
            s += v; s2 += v * v;
        }
        ls[tid] = s; ls2[tid] = s2;
    }
    __syncthreads();
    if (tid < 80) {
        atomicAdd(&gsum[tid],   ls[tid] + ls[tid + 80] + ls[tid + 160]);
        atomicAdd(&gsumsq[tid], ls2[tid] + ls2[tid + 80] + ls2[tid + 160]);
    }
}

__global__ void bn_apply(const float* __restrict__ x, const float* __restrict__ gsum,
                         const float* __restrict__ gsumsq, const float* __restrict__ gamma,
                         const float* __restrict__ beta, f16* __restrict__ xpad)
{
    long idx = (long)blockIdx.x * 256 + threadIdx.x;
    if (idx >= (long)NB * TIN * CIN) return;
    int c = (int)(idx % CIN);
    long bt = idx / CIN;
    int t = (int)(bt % TIN); int b = (int)(bt / TIN);
    float mean = gsum[c] * (1.f / 51200.f);
    float var  = gsumsq[c] * (1.f / 51200.f) - mean * mean;
    float sc = gamma[c] * rsqrtf(var + EPSB);
    float sh = beta[c] - mean * sc;
    xpad[((long)b * TXP + t + 1) * CIN + c] = (f16)(x[idx] * sc + sh);
}

// ---------------------------------------------------------------- generic fp16 MFMA GEMM (64x128 tile) — tail use only
// MODE 2: attention scores (f32)   MODE 3: fc (bias -> f32 logits in d_out)
template<int MODE>
__launch_bounds__(256)
__global__ void gemm16(const f16* __restrict__ Ab, long strideA, long slabA,
                       const f16* __restrict__ Bb, long strideB, long slabB,
                       int M, int N, int Kchunks,
                       const float* __restrict__ bias,
                       float* __restrict__ outF)
{
    __shared__ f16 As[64][72];
    __shared__ f16 Bs[128][72];
    const int b = blockIdx.z;
    const f16* Abase = Ab + (long)b * slabA;
    const f16* Bbase = Bb + (long)b * slabB;
    const int m0 = blockIdx.x * 64, n0 = blockIdx.y * 128;
    const int tid = threadIdx.x;
    const int lane = tid & 63, wv = tid >> 6;
    const int lm = lane & 15, lk = lane >> 4;

    f32x4 vzero = {0.f, 0.f, 0.f, 0.f};
    f32x4 acc[4][2];
#pragma unroll
    for (int i = 0; i < 4; i++) { acc[i][0] = vzero; acc[i][1] = vzero; }

    const int srow = tid >> 3, scol = (tid & 7) * 8;

    for (int kc = 0; kc < Kchunks; kc++) {
        int kb = kc * 64;
#pragma unroll
        for (int p = 0; p < 2; p++) {
            int r = srow + p * 32;
            int m = m0 + r; if (m > M - 1) m = M - 1;
            *(us8*)&As[r][scol] = *(const us8*)(Abase + (long)m * strideA + kb + scol);
        }
#pragma unroll
        for (int p = 0; p < 4; p++) {
            int r = srow + p * 32;
            int n = n0 + r; if (n > N - 1) n = N - 1;
            *(us8*)&Bs[r][scol] = *(const us8*)(Bbase + (long)n * strideB + kb + scol);
        }
        __syncthreads();
#pragma unroll
        for (int ks = 0; ks < 2; ks++) {
            f16x8 af[4], bf[2];
#pragma unroll
            for (int mt = 0; mt < 4; mt++)
                af[mt] = *(const f16x8*)&As[mt * 16 + lm][ks * 32 + lk * 8];
#pragma unroll
            for (int nt = 0; nt < 2; nt++)
                bf[nt] = *(const f16x8*)&Bs[wv * 32 + nt * 16 + lm][ks * 32 + lk * 8];
#pragma unroll
            for (int mt = 0; mt < 4; mt++)
#pragma unroll
                for (int nt = 0; nt < 2; nt++)
                    acc[mt][nt] = __builtin_amdgcn_mfma_f32_16x16x32_f16(af[mt], bf[nt], acc[mt][nt], 0, 0, 0);
        }
        __syncthreads();
    }
#pragma unroll
    for (int mt = 0; mt < 4; mt++) {
#pragma unroll
        for (int nt = 0; nt < 2; nt++) {
            int n = n0 + wv * 32 + nt * 16 + lm;
#pragma unroll
            for (int reg = 0; reg < 4; reg++) {
                int m = m0 + mt * 16 + lk * 4 + reg;
                if (m >= M || n >= N) continue;
                float v = acc[mt][nt][reg];
                if (MODE == 2) {
                    outF[((long)b * NU + m) * 800 + n] = v;
                } else {
                    v += bias[n];
                    int u = m >> 5, bb = m & 31;
                    outF[((long)bb * NU + u) * 1000 + n] = v;
                }
            }
        }
    }
}

// ---------------------------------------------------------------- encoder layer worker (inside fused kernel)
// One layer = 1664 tiles (32 batches x 13 Mtiles x 4 Ntiles), M=800, N=512.
__device__ void enc_layer(int eb, int tid,
                          const f16* __restrict__ Ab, long strideA, long slabA,
                          const f16* __restrict__ Bb, long strideB,
                          int Kchunks, const float* __restrict__ bias,
                          const f16* __restrict__ resid, f16* __restrict__ outH,
                          long slabRO, f16 As[][72], f16 Bs[][72])
{
    const int lane = tid & 63, wv = tid >> 6;
    const int lm = lane & 15, lk = lane >> 4;
    const int srow = tid >> 3, scol = (tid & 7) * 8;
    f32x4 vzero = {0.f, 0.f, 0.f, 0.f};

    for (int t = eb; t < 1664; t += EWG) {
        int b = t / 52, rem = t - b * 52;
        int m0 = (rem >> 2) * 64, n0 = (rem & 3) * 128;
        const f16* Abase = Ab + (long)b * slabA;

        f32x4 acc[4][2];
#pragma unroll
        for (int i = 0; i < 4; i++) { acc[i][0] = vzero; acc[i][1] = vzero; }

        for (int kc = 0; kc < Kchunks; kc++) {
            int kb = kc * 64;
#pragma unroll
            for (int p = 0; p < 2; p++) {
                int r = srow + p * 32;
                int m = m0 + r; if (m > 799) m = 799;
                *(us8*)&As[r][scol] = *(const us8*)(Abase + (long)m * strideA + kb + scol);
            }
#pragma unroll
            for (int p = 0; p < 4; p++) {
                int r = srow + p * 32;
                *(us8*)&Bs[r][scol] = *(const us8*)(Bb + (long)(n0 + r) * strideB + kb + scol);
            }
            __syncthreads();
#pragma unroll
            for (int ks = 0; ks < 2; ks++) {
                f16x8 af[4], bf[2];
#pragma unroll
                for (int mt = 0; mt < 4; mt++)
                    af[mt] = *(const f16x8*)&As[mt * 16 + lm][ks * 32 + lk * 8];
#pragma unroll
                for (int nt = 0; nt < 2; nt++)
                    bf[nt] = *(const f16x8*)&Bs[wv * 32 + nt * 16 + lm][ks * 32 + lk * 8];
#pragma unroll
                for (int mt = 0; mt < 4; mt++)
#pragma unroll
                    for (int nt = 0; nt < 2; nt++)
                        acc[mt][nt] = __builtin_amdgcn_mfma_f32_16x16x32_f16(af[mt], bf[nt], acc[mt][nt], 0, 0, 0);
            }
            __syncthreads();
        }
#pragma unroll
        for (int mt = 0; mt < 4; mt++) {
#pragma unroll
            for (int nt = 0; nt < 2; nt++) {
                int n = n0 + wv * 32 + nt * 16 + lm;
#pragma unroll
                for (int reg = 0; reg < 4; reg++) {
                    int m = m0 + mt * 16 + lk * 4 + reg;
                    if (m >= 800) continue;
                    float v = acc[mt][nt][reg] + bias[n];
                    v = v > 0.f ? v : 0.f;
                    if (resid) v += (float)resid[(long)b * slabRO + (long)(2 + m) * DH + n];
                    outH[(long)b * slabRO + (long)(2 + m) * DH + n] = (f16)v;
                }
            }
        }
    }
}

// ---------------------------------------------------------------- fused: blocks 0..7 = GRU (R8-proven sentinel exchange:
// two sequential 16-load polls, A-first stores), blocks 8..255 = persistent encoder workers.
__launch_bounds__(256, 1)
__global__ void enc_gru(const f16* __restrict__ wrecT, const float* __restrict__ gk,
                        const float* __restrict__ gbias, const int* __restrict__ ytrue,
                        f16* __restrict__ Hc,
                        const f16* __restrict__ xpad, const f16* __restrict__ w0T,
                        const float* __restrict__ b0, const f16* __restrict__ tcrT,
                        const float* __restrict__ tcrb,
                        f16* __restrict__ hbufA, f16* __restrict__ hbufB,
                        int* __restrict__ lcnt)
{
    const int tid = threadIdx.x;

    if (blockIdx.x < 8) {
        // ==================== GRU ====================
        __shared__ int yl[NU * 32];
        const int lane = tid & 63, wv = tid >> 6;
        const int gw = (int)blockIdx.x * 4 + wv;
        const int lm = lane & 15, lk = lane >> 4;
        const int j = gw * 16 + lm;

        for (int i = tid; i < NU * 32; i += 256) {
            int b = i / NU, u = i - b * NU;
            yl[u * 32 + b] = ytrue[b * 201 + u];
        }

        f16x8 wf[3][16];
#pragma unroll
        for (int g = 0; g < 3; g++)
#pragma unroll
            for (int ks = 0; ks < 16; ks++) {
                wf[g][ks] = *(const f16x8*)&wrecT[(long)(g * 512 + j) * 512 + ks * 32 + lk * 8];
                asm volatile("" : "+v"(wf[g][ks]));
            }

        const float biz = gbias[j],        bir = gbias[512 + j],        bic = gbias[1024 + j];
        const float brz = gbias[1536 + j], brr = gbias[1536 + 512 + j], brc = gbias[1536 + 1024 + j];
        f32x4 vzero = {0.f, 0.f, 0.f, 0.f};

        __syncthreads();

        float hold[8];
        float nxz[8], nxr[8], nxh[8], mxz[8], mxr[8], mxh[8];
#pragma unroll
        for (int s = 0; s < 8; s++) {
            hold[s] = 0.f;
            int b = ((s >> 2) << 4) + lk * 4 + (s & 3);
            const float* gkr = gk + (long)yl[b] * 1536;
            nxz[s] = gkr[j]; nxr[s] = gkr[512 + j]; nxh[s] = gkr[1024 + j];
        }

        for (int u = 0; u < NU; u++) {
            int up = (u < NU - 1) ? u + 1 : u;
#pragma unroll
            for (int s = 0; s < 8; s++) {
                int b = ((s >> 2) << 4) + lk * 4 + (s & 3);
                const float* gkr = gk + (long)yl[up * 32 + b] * 1536;
                mxz[s] = gkr[j]; mxr[s] = gkr[512 + j]; mxh[s] = gkr[1024 + j];
            }

            f32x4 acc[3][2];
#pragma unroll
            for (int g = 0; g < 3; g++) { acc[g][0] = vzero; acc[g][1] = vzero; }

            if (u > 0) {
                const f16* baseA = Hc + ((long)(u - 1) * 32 + lm) * 1024 + lk * 8;
                // batch A: rows lm (batches 0..15) — consume fully before loading batch B
                {
                    f16x8 va[16];
                    poll_h16(baseA, va);
#pragma unroll
                    for (int ks = 0; ks < 16; ks++)
#pragma unroll
                        for (int g = 0; g < 3; g++)
                            acc[g][0] = __builtin_amdgcn_mfma_f32_16x16x32_f16(va[ks], wf[g][ks], acc[g][0], 0, 0, 0);
                }
                // batch B: rows 16+lm (batches 16..31)
                {
                    f16x8 vb[16];
                    poll_h16(baseA + 16 * 1024, vb);
#pragma unroll
                    for (int ks = 0; ks < 16; ks++)
#pragma unroll
                        for (int g = 0; g < 3; g++)
                            acc[g][1] = __builtin_amdgcn_mfma_f32_16x16x32_f16(vb[ks], wf[g][ks], acc[g][1], 0, 0, 0);
                }
            }

#pragma unroll
            for (int mt = 0; mt < 2; mt++) {
#pragma unroll
                for (int reg = 0; reg < 4; reg++) {
                    int s = mt * 4 + reg;
                    int b = mt * 16 + lk * 4 + reg;
                    float hz = acc[0][mt][reg] + brz;
                    float hr = acc[1][mt][reg] + brr;
                    float hh = acc[2][mt][reg] + brc;
                    float z = 1.f / (1.f + __expf(-(nxz[s] + biz + hz)));
                    float r = 1.f / (1.f + __expf(-(nxr[s] + bir + hr)));
                    float cd = fast_tanh(nxh[s] + bic + r * hh);
                    float hnew = z * hold[s] + (1.f - z) * cd;
                    hold[s] = hnew;
                    st_sys_f16(&Hc[((long)u * 32 + b) * 1024 + j], hnew);
                }
            }
#pragma unroll
            for (int s = 0; s < 8; s++) { nxz[s] = mxz[s]; nxr[s] = mxr[s]; nxh[s] = mxh[s]; }
            // no flag, no drain, no barrier: readers gate on the data itself
        }
        asm volatile("s_waitcnt vmcnt(0)" ::: "memory");
        return;
    }

    // ==================== encoder workers ====================
    __shared__ f16 As[64][72];
    __shared__ f16 Bs[128][72];
    const int eb = (int)blockIdx.x - 8;

    // layer 0: conv0
    enc_layer(eb, tid, xpad, 160, (long)TXP * CIN, w0T, 448, 7, b0,
              nullptr, hbufA, (long)THP * DH, As, Bs);

    const f16* tin = hbufA; f16* tout = hbufB;
    for (int L = 0; L < 4; L++) {
        // barrier: publish layer L-output (release), wait all, invalidate (acquire)
        __syncthreads();
        if (tid == 0) {
            __hip_atomic_fetch_add(&lcnt[L], 1, __ATOMIC_RELEASE, __HIP_MEMORY_SCOPE_AGENT);
            while (__hip_atomic_load(&lcnt[L], __ATOMIC_RELAXED, __HIP_MEMORY_SCOPE_AGENT) < EWG)
                __builtin_amdgcn_s_sleep(8);
            (void)__hip_atomic_load(&lcnt[L], __ATOMIC_ACQUIRE, __HIP_MEMORY_SCOPE_AGENT);
        }
        __syncthreads();

        enc_layer(eb, tid, tin, 512, (long)THP * DH, tcrT + (size_t)L * 512 * 2560, 2560,
                  40, tcrb + L * 512, tin, tout, (long)THP * DH, As, Bs);
        const f16* t2 = tout; tout = (f16*)tin; tin = t2;
    }
    // final output in hbufA; kernel-end flush publishes it to later dispatches
}

// ---------------------------------------------------------------- row softmax in place (len <= 1024) — final output only
__global__ void row_softmax(float* __restrict__ base, int len)
{
    float* s = base + (long)blockIdx.x * len;
    int tid = threadIdx.x;
    float v[4]; float mx = -1e30f;
#pragma unroll
    for (int i = 0; i < 4; i++) {
        int idx = tid + i * 256;
        v[i] = (idx < len) ? s[idx] : -1e30f;
        mx = fmaxf(mx, v[i]);
    }
#pragma unroll
    for (int off = 32; off; off >>= 1) mx = fmaxf(mx, __shfl_xor(mx, off));
    __shared__ float red[4], red2[4];
    if ((tid & 63) == 0) red[tid >> 6] = mx;
    __syncthreads();
    mx = fmaxf(fmaxf(red[0], red[1]), fmaxf(red[2], red[3]));
    float sum = 0.f;
#pragma unroll
    for (int i = 0; i < 4; i++) { v[i] = __expf(v[i] - mx); sum += v[i]; }
#pragma unroll
    for (int off = 32; off; off >>= 1) sum += __shfl_xor(sum, off);
    if ((tid & 63) == 0) red2[tid >> 6] = sum;
    __syncthreads();
    sum = red2[0] + red2[1] + red2[2] + red2[3];
    float inv = 1.f / sum;
#pragma unroll
    for (int i = 0; i < 4; i++) {
        int idx = tid + i * 256;
        if (idx < len) s[idx] = v[i] * inv;
    }
}

// ---------------------------------------------------------------- ctx with FUSED softmax (R6/R8-validated): reads RAW
// scores, softmaxes each row (identical FP op order to row_softmax -> bit-identical alpha), then ctx = alpha @ enc.
// Deletes the standalone 6400-row softmax pass over the 204.8 MB scores buffer.
__global__ void ctx_kernel(const float* __restrict__ scores, const f16* __restrict__ enc,
                           f16* __restrict__ Hc)
{
    __shared__ float al[800][18];
    __shared__ float red[4], red2[4];
    int b = blockIdx.x, ut = blockIdx.y;
    int u0 = ut * 16;
    int tid = threadIdx.x;
    for (int ul = 0; ul < 16; ul++) {
        int u = u0 + ul;
        if (u < NU) {
            const float* arow = scores + ((long)b * NU + u) * 800;
            float v[4]; float mx = -1e30f;
#pragma unroll
            for (int i = 0; i < 4; i++) {
                int idx = tid + i * 256;
                v[i] = (idx < 800) ? arow[idx] : -1e30f;
                mx = fmaxf(mx, v[i]);
            }
#pragma unroll
            for (int off = 32; off; off >>= 1) mx = fmaxf(mx, __shfl_xor(mx, off));
            if ((tid & 63) == 0) red[tid >> 6] = mx;
            __syncthreads();
            mx = fmaxf(fmaxf(red[0], red[1]), fmaxf(red[2], red[3]));
            float sum = 0.f;
#pragma unroll
            for (int i = 0; i < 4; i++) { v[i] = __expf(v[i] - mx); sum += v[i]; }
#pragma unroll
            for (int off = 32; off; off >>= 1) sum += __shfl_xor(sum, off);
            if ((tid & 63) == 0) red2[tid >> 6] = sum;
            __syncthreads();
            sum = red2[0] + red2[1] + red2[2] + red2[3];
            float inv = 1.f / sum;
#pragma unroll
            for (int i = 0; i < 4; i++) {
                int idx = tid + i * 256;
                if (idx < 800) al[idx][ul] = v[i] * inv;
            }
            __syncthreads();   // red/red2 reuse safety (uniform branch: u depends only on blockIdx/ul)
        } else {
            for (int t = tid; t < 800; t += 256) al[t][ul] = 0.f;
        }
    }
    __syncthreads();
    int d0 = tid * 2;
    float a0[16], a1[16];
#pragma unroll
    for (int i = 0; i < 16; i++) { a0[i] = 0.f; a1[i] = 0.f; }
    const f16* encb = enc + ((long)b * THP + 2) * DH + d0;
    for (int t = 0; t < 800; t++) {
        f16x2 e = *(const f16x2*)&encb[(long)t * DH];
        float f0 = (float)e.x, f1 = (float)e.y;
#pragma unroll
        for (int g = 0; g < 8; g++) {
            f32x2 ap = *(const f32x2*)&al[t][2 * g];
            a0[2 * g]     += ap.x * f0; a0[2 * g + 1] += ap.y * f0;
            a1[2 * g]     += ap.x * f1; a1[2 * g + 1] += ap.y * f1;
        }
    }
#pragma unroll
    for (int ul = 0; ul < 16; ul++) {
        int u = u0 + ul;
        if (u < NU) {
            Hc[((long)u * 32 + b) * 1024 + 512 + d0]     = (f16)a0[ul];
            Hc[((long)u * 32 + b) * 1024 + 512 + d0 + 1] = (f16)a1[ul];
        }
    }
}

// ---------------------------------------------------------------- launcher
extern "C" void kernel_launch(void* const* d_in, const int* in_sizes, int n_in,
                              void* d_out, int out_size, void* d_ws, size_t ws_size,
                              hipStream_t stream)
{
    const float* x     = (const float*)d_in[0];
    const int*   ytrue = (const int*)d_in[1];
    const float* gamma = (const float*)d_in[2];
    const float* beta  = (const float*)d_in[3];
    const float* w0    = (const float*)d_in[4];
    const float* b0    = (const float*)d_in[5];
    const float* tcrw  = (const float*)d_in[6];
    const float* tcrb  = (const float*)d_in[7];
    const float* gk    = (const float*)d_in[8];
    const float* grk   = (const float*)d_in[9];
    const float* gbias = (const float*)d_in[10];
    const float* fcw   = (const float*)d_in[11];
    const float* fcb   = (const float*)d_in[12];
    float* out = (float*)d_out;
    (void)in_sizes; (void)n_in; (void)out_size; (void)ws_size;

    char* ws = (char*)d_ws;
    size_t o = 0;
    auto alloc = [&](size_t bytes) { size_t r = o; o += (bytes + 255) & ~(size_t)255; return r; };
    f16*   xpad   = (f16*)(ws + alloc((size_t)NB * TXP * CIN * 2));
    f16*   hbufA  = (f16*)(ws + alloc((size_t)NB * THP * DH * 2));
    f16*   hbufB  = (f16*)(ws + alloc((size_t)NB * THP * DH * 2));
    f16*   Hc     = (f16*)(ws + alloc((size_t)NU * NB * 1024 * 2));
    float* scores = (float*)(ws + alloc((size_t)NB * NU * 800 * 4));
    f16*   w0T    = (f16*)(ws + alloc((size_t)512 * 448 * 2));
    f16*   tcrT   = (f16*)(ws + alloc((size_t)4 * 512 * 2560 * 2));
    f16*   wrecT  = (f16*)(ws + alloc((size_t)1536 * 512 * 2));
    f16*   fcT    = (f16*)(ws + alloc((size_t)1024 * 1024 * 2));
    float* gsum   = (float*)(ws + alloc(80 * 4));
    float* gsumsq = (float*)(ws + alloc(80 * 4));
    int*   lcnt   = (int*)(ws + alloc(64));

    // fused prep: init + all weight transposes in one dispatch
    prep<<<7200, 256, 0, stream>>>(gsum, gsumsq, lcnt, xpad, hbufA, hbufB, Hc,
                                   w0, w0T, tcrw, tcrT, grk, wrecT, fcw, fcT);

    bn_stats<<<256, 256, 0, stream>>>(x, gsum, gsumsq);
    bn_apply<<<16000, 256, 0, stream>>>(x, gsum, gsumsq, gamma, beta, xpad);

    // fused: GRU (blocks 0..7) + encoder conv chain (blocks 8..255)
    enc_gru<<<8 + EWG, 256, 0, stream>>>(wrecT, gk, gbias, ytrue, Hc,
                                         xpad, w0T, b0, tcrT, tcrb, hbufA, hbufB, lcnt);
    const f16* enc = hbufA;   // after 4 ping-pong swaps

    // scores[b][u][t] = Hc[u][b][:512] . enc[b][t][:]  (raw logits; softmax fused into ctx)
    gemm16<2><<<dim3(4, 7, 32), 256, 0, stream>>>(Hc, 32 * 1024, 1024, enc + 2 * DH, 512, (long)THP * DH,
        200, 800, 8, nullptr, scores);
    ctx_kernel<<<dim3(32, 13), 256, 0, stream>>>(scores, enc, Hc);

    // logits[b][u][v] = Hc_row(u*32+b)[0:1024] @ fcT + fc_b  -> d_out
    gemm16<3><<<dim3(100, 8, 1), 256, 0, stream>>>(Hc, 1024, 0, fcT, 1024, 0,
        6400, 1000, 16, fcb, out);
    row_softmax<<<6400, 256, 0, stream>>>(out, 1000);
}